// Round 11
// baseline (163.652 us; speedup 1.0000x reference)
//
#include <hip/hip_runtime.h>
#include <hip/hip_bf16.h>
#include <math.h>

// Problem constants (B=8, H=W=256, C=32, WIN=8, HEADS=2, DH=16, HIDDEN=128)
#define IMG   256
#define HWTOK 65536
#define CH    32

typedef __attribute__((ext_vector_type(8))) _Float16 half8v;    // 8 fp16
typedef __attribute__((ext_vector_type(2))) _Float16 half2v;    // 2 fp16
typedef __attribute__((ext_vector_type(4))) float floatx4;

__device__ __forceinline__ unsigned short f2h(float f) {
    _Float16 h = (_Float16)f;
    return __builtin_bit_cast(unsigned short, h);
}
__device__ __forceinline__ float h2f(unsigned short u) {
    return (float)__builtin_bit_cast(_Float16, u);
}
__device__ __forceinline__ unsigned packh2(float a, float b) {
    return (unsigned)f2h(a) | ((unsigned)f2h(b) << 16);
}

// GELU via odd Taylor of Phi(v) = 0.5 + v*p(v^2), packed fp16. (round-10 form)
__device__ __forceinline__ half2v gelu2v(half2v v) {
    const half2v hi = (half2v)(_Float16)( 2.0f);
    const half2v lo = (half2v)(_Float16)(-2.0f);
    const half2v vc = __builtin_elementwise_min(__builtin_elementwise_max(v, lo), hi);
    const half2v s  = vc * vc;
    half2v p = s * (half2v)(_Float16)(-1.18726e-3f) + (half2v)(_Float16)(9.97356e-3f);
    p = s * p + (half2v)(_Float16)(-6.64904e-2f);
    p = s * p + (half2v)(_Float16)( 3.989423e-1f);
    return v * (vc * p + (half2v)(_Float16)(0.5f));
}

// ---------------------------------------------------------------------------
// Prep: one-shot weight marshalling (fp16, pre-transposed/permuted) into ws.
// w1p[row][k] (row = permuted hidden col), w2p[n][k] = w2^T.  4096 elems each.
// ---------------------------------------------------------------------------
__global__ __launch_bounds__(256) void prep_kernel(
    const float* __restrict__ w1, const float* __restrict__ w2,
    unsigned short* __restrict__ w1p, unsigned short* __restrict__ w2p)
{
    const int tid = blockIdx.x * 256 + threadIdx.x;
    if (tid < 4096) {
        const int row = tid >> 5, k = tid & 31;
        const int bl = row >> 5, wi = row & 31;
        const int j = bl * 32 + ((wi & 15) << 1) + (wi >> 4);   // perm(row)
        w1p[tid] = f2h(w1[k * 128 + j]);
        const int n = tid >> 7, kk = tid & 127;
        w2p[tid] = f2h(w2[kk * 32 + n]);
    }
}

// ---------------------------------------------------------------------------
// Kernel 1: LN1 + window attention + proj + residual.  (unchanged from R10)
// ---------------------------------------------------------------------------
__global__ __launch_bounds__(256) void attn_kernel(
    const float* __restrict__ x,
    const float* __restrict__ n1g, const float* __restrict__ n1b,
    const float* __restrict__ wq,  const float* __restrict__ bq,
    const float* __restrict__ wkv, const float* __restrict__ bkv,
    const float* __restrict__ wo,  const float* __restrict__ bo,
    const float* __restrict__ relb,
    float* __restrict__ x1)
{
    struct Win {
        union {
            unsigned short xn[64][40];
            unsigned short P[2][64][72];
            unsigned short O[64][40];
        } u;
        unsigned short Q[64][40];
        unsigned short K[64][56];
        unsigned short VT[2][16][72];
    };
    __shared__ Win W[2];
    __shared__ unsigned short bias16[2][228];
    __shared__ float denom[2][2][64];

    const int tid = threadIdx.x;
    const int wv  = tid >> 6;
    const int w   = wv >> 1;
    const int h   = wv & 1;
    const int l   = tid & 63;
    const int lm  = l & 15, lq = l >> 4;
    Win& S = W[w];

    const int win = blockIdx.x * 2 + w;
    const int b   = win >> 10;
    const int wh  = (win >> 5) & 31, ww = win & 31;
    const size_t wbase = ((size_t)b * HWTOK + (wh * 8) * IMG + ww * 8) * CH;

    const float LOG2E = 1.4426950408889634f;
    const float QSC   = 0.25f * LOG2E;

    half8v bwq, bwk, bwv, bwo0, bwo1;
    {
        const int lq8 = lq * 8;
        #pragma unroll
        for (int i = 0; i < 8; ++i) {
            bwq[i]  = (_Float16)(wq[(lq8 + i) * 32 + h * 16 + lm] * QSC);
            bwk[i]  = (_Float16)wkv[(lq8 + i) * 64 + h * 16 + lm];
            bwv[i]  = (_Float16)wkv[(lq8 + i) * 64 + 32 + h * 16 + lm];
            bwo0[i] = (_Float16)wo [(lq8 + i) * 32 + lm];
            bwo1[i] = (_Float16)wo [(lq8 + i) * 32 + 16 + lm];
        }
    }

    if (tid < 128) {
        const int sw = tid >> 6, st = tid & 63;
        Win& SS = W[sw];
        const int swin = blockIdx.x * 2 + sw;
        const int sb = swin >> 10, swh = (swin >> 5) & 31, sww = swin & 31;
        const size_t sbase = ((size_t)sb * HWTOK
                            + (swh * 8 + (st >> 3)) * IMG + sww * 8 + (st & 7)) * CH;
        const float4* xp = (const float4*)(x + sbase);
        float xr[32];
        float mu = 0.f;
        #pragma unroll
        for (int i = 0; i < 8; ++i) {
            const float4 v = xp[i];
            xr[i*4+0]=v.x; xr[i*4+1]=v.y; xr[i*4+2]=v.z; xr[i*4+3]=v.w;
            mu += v.x + v.y + v.z + v.w;
        }
        mu *= (1.f / 32.f);
        float var = 0.f;
        #pragma unroll
        for (int c = 0; c < 32; ++c) { const float d = xr[c] - mu; var += d * d; }
        const float inv = rsqrtf(var * (1.f / 32.f) + 1e-5f);
        unsigned int pk[16];
        #pragma unroll
        for (int j = 0; j < 16; ++j)
            pk[j] = packh2((xr[2*j]   - mu) * inv * n1g[2*j]   + n1b[2*j],
                           (xr[2*j+1] - mu) * inv * n1g[2*j+1] + n1b[2*j+1]);
        uint4* dst = (uint4*)&SS.u.xn[st][0];
        #pragma unroll
        for (int j = 0; j < 4; ++j) dst[j] = *(uint4*)&pk[j * 4];
        const uint4 z = {0u, 0u, 0u, 0u};
        *(uint4*)&SS.K[st][16] = z;
        *(uint4*)&SS.K[st][24] = z;
    } else {
        const int t2 = tid - 128;
        for (int i = t2; i < 450; i += 128) {
            const int hh = (i >= 225), r = i - hh * 225;
            bias16[hh][r] = f2h(relb[r * 2 + hh] * LOG2E);
        }
    }
    __syncthreads();

    const float bqv = bq[h*16 + lm] * QSC;
    const float bkv_ = bkv[h*16 + lm];
    const float bvv = bkv[32 + h*16 + lm];
    const floatx4 cq = {bqv, bqv, bqv, bqv};
    const floatx4 ck = {bkv_, bkv_, bkv_, bkv_};
    const floatx4 cv = {bvv, bvv, bvv, bvv};
    const floatx4 zero = {0.f, 0.f, 0.f, 0.f};

    #pragma unroll
    for (int mt = 0; mt < 4; ++mt) {
        const half8v a = *(const half8v*)&S.u.xn[mt*16 + lm][lq*8];
        const floatx4 dq = __builtin_amdgcn_mfma_f32_16x16x32_f16(a, bwq, cq, 0,0,0);
        const floatx4 dk = __builtin_amdgcn_mfma_f32_16x16x32_f16(a, bwk, ck, 0,0,0);
        const floatx4 dv = __builtin_amdgcn_mfma_f32_16x16x32_f16(a, bwv, cv, 0,0,0);
        const int r0 = mt*16 + lq*4;
        #pragma unroll
        for (int r = 0; r < 4; ++r) {
            S.Q[r0 + r][h*16 + lm] = f2h(dq[r]);
            S.K[r0 + r][h*32 + lm] = f2h(dk[r]);
        }
        uint2 vv;
        vv.x = packh2(dv[0], dv[1]);
        vv.y = packh2(dv[2], dv[3]);
        *(uint2*)&S.VT[h][lm][r0] = vv;
    }
    __syncthreads();

    half8v ak[4], bqf[4];
    #pragma unroll
    for (int mt = 0; mt < 4; ++mt)
        ak[mt] = *(const half8v*)&S.K[mt*16 + lm][h*16 + lq*8];
    #pragma unroll
    for (int nt = 0; nt < 4; ++nt)
        bqf[nt] = *(const half8v*)&S.Q[nt*16 + lm][lq*8];

    const int cc0 = (lm >> 3) * 15 + (lm & 7);
    const int cml = 15 * (lq >> 1) + 4 * (lq & 1);

    #pragma unroll
    for (int nt = 0; nt < 4; ++nt) {
        float sum = 0.f;
        const int base_nt = 30*nt + cc0 + 112 - cml;
        #pragma unroll
        for (int mt = 0; mt < 4; ++mt) {
            const floatx4 d = __builtin_amdgcn_mfma_f32_16x16x32_f16(ak[mt], bqf[nt], zero, 0,0,0);
            const int ib = base_nt - 30*mt;
            const float e0 = exp2f(d[0] + h2f(bias16[h][ib]));
            const float e1 = exp2f(d[1] + h2f(bias16[h][ib - 1]));
            const float e2 = exp2f(d[2] + h2f(bias16[h][ib - 2]));
            const float e3 = exp2f(d[3] + h2f(bias16[h][ib - 3]));
            sum += (e0 + e1) + (e2 + e3);
            uint2 pw;
            pw.x = packh2(e0, e1);
            pw.y = packh2(e2, e3);
            *(uint2*)&S.u.P[h][nt*16 + lm][mt*16 + lq*4] = pw;
        }
        sum += __shfl_xor(sum, 16);
        sum += __shfl_xor(sum, 32);
        if (l < 16) denom[w][h][nt*16 + l] = __frcp_rn(sum);
    }

    const half8v bva = *(const half8v*)&S.VT[h][lm][lq*8];
    const half8v bvb = *(const half8v*)&S.VT[h][lm][32 + lq*8];
    float oreg[16];
    #pragma unroll
    for (int mt = 0; mt < 4; ++mt) {
        const half8v ap0 = *(const half8v*)&S.u.P[h][mt*16 + lm][lq*8];
        const half8v ap1 = *(const half8v*)&S.u.P[h][mt*16 + lm][32 + lq*8];
        floatx4 ov = __builtin_amdgcn_mfma_f32_16x16x32_f16(ap0, bva, zero, 0,0,0);
        ov         = __builtin_amdgcn_mfma_f32_16x16x32_f16(ap1, bvb, ov,   0,0,0);
        const float4 dn = *(const float4*)&denom[w][h][mt*16 + lq*4];
        oreg[mt*4+0] = ov[0] * dn.x;
        oreg[mt*4+1] = ov[1] * dn.y;
        oreg[mt*4+2] = ov[2] * dn.z;
        oreg[mt*4+3] = ov[3] * dn.w;
    }
    __syncthreads();

    #pragma unroll
    for (int mt = 0; mt < 4; ++mt)
        #pragma unroll
        for (int r = 0; r < 4; ++r)
            S.u.O[mt*16 + lq*4 + r][h*16 + lm] = f2h(oreg[mt*4 + r]);
    __syncthreads();

    const float bo0 = bo[lm], bo1 = bo[16 + lm];
    const floatx4 co0 = {bo0, bo0, bo0, bo0};
    const floatx4 co1 = {bo1, bo1, bo1, bo1};
    #pragma unroll
    for (int mi = 0; mi < 2; ++mi) {
        const int mt = 2*h + mi;
        const half8v aO = *(const half8v*)&S.u.O[mt*16 + lm][lq*8];
        const floatx4 d0 = __builtin_amdgcn_mfma_f32_16x16x32_f16(aO, bwo0, co0, 0,0,0);
        const floatx4 d1 = __builtin_amdgcn_mfma_f32_16x16x32_f16(aO, bwo1, co1, 0,0,0);
        #pragma unroll
        for (int r = 0; r < 4; ++r) {
            const int t = mt*16 + lq*4 + r;
            const size_t g = wbase + (size_t)((t >> 3) * IMG + (t & 7)) * CH;
            x1[g + lm]      = x[g + lm]      + d0[r];
            x1[g + 16 + lm] = x[g + 16 + lm] + d1[r];
        }
    }
}

// ---------------------------------------------------------------------------
// Kernel 2 (primary): fused LeFF with GLOBAL fp16 weights (prep kernel).
// No w1T/w2T LDS staging: B-frags read directly from w1p/w2p (L2-hot).
// LDS = union{xnA 8.9K, glA[64][132] 16.9K} + hid[100][132] 26.4K = 43.3 KB
// -> 3 blocks/CU even under a 128 KB schedulable-pool hypothesis.
// ---------------------------------------------------------------------------
__global__ __launch_bounds__(256, 3) void leff_kernel_gw(
    const float* __restrict__ x1,
    const float* __restrict__ n2g, const float* __restrict__ n2b,
    const float* __restrict__ b1,
    const float* __restrict__ dw,  const float* __restrict__ dwb,
    const float* __restrict__ b2,
    const unsigned short* __restrict__ w1p,
    const unsigned short* __restrict__ w2p,
    float* __restrict__ out)
{
    union SharedU {
        unsigned short xnA[112][40];    // phase 1 A panel
        unsigned short glA[64][132];    // phase 3 A panel
    };
    __shared__ __align__(16) SharedU u;                     // 16896 B
    __shared__ __align__(16) unsigned short hid[100][132];  // 26400 B

    const int blk = blockIdx.x;
    const int b = blk >> 10, tyb = (blk >> 5) & 31, txb = blk & 31;
    const int y0 = tyb * 8, x0 = txb * 8;
    const int tid = threadIdx.x;
    const int wv = tid >> 6;
    const int l  = tid & 63;
    const int lm = l & 15;
    const int lq = l >> 4;
    const bool edge = (tyb == 0) | (tyb == 31) | (txb == 0) | (txb == 31);

    // ---- hoisted global weight B-frags (independent of LDS phases) ----
    const half8v bf0 = *(const half8v*)&w1p[(wv * 32 + lm) * 32 + lq * 8];
    const half8v bf1 = *(const half8v*)&w1p[(wv * 32 + 16 + lm) * 32 + lq * 8];
    half8v w2f[2][4];
    #pragma unroll
    for (int nt = 0; nt < 2; ++nt)
        #pragma unroll
        for (int kc = 0; kc < 4; ++kc)
            w2f[nt][kc] = *(const half8v*)&w2p[(nt*16 + lm) * 128 + kc*32 + lq*8];

    // ---- P0: LN2, 2 threads per halo pixel ----
    if (tid < 200) {
        const int px = tid >> 1, half = tid & 1;
        const int hy = px / 10, hx = px % 10;
        const int iy = y0 + hy - 1, ix = x0 + hx - 1;
        const bool inb = (iy >= 0 && iy < IMG && ix >= 0 && ix < IMG);
        unsigned int pk[8];
        if (inb) {
            const size_t base = ((size_t)b * HWTOK + iy * IMG + ix) * CH + half * 16;
            const float4* xp = (const float4*)(x1 + base);
            float v[16];
            float s = 0.f;
            #pragma unroll
            for (int i = 0; i < 4; ++i) {
                const float4 t = xp[i];
                v[i*4+0]=t.x; v[i*4+1]=t.y; v[i*4+2]=t.z; v[i*4+3]=t.w;
                s += t.x + t.y + t.z + t.w;
            }
            const float mu = (s + __shfl_xor(s, 1)) * (1.f / 32.f);
            float q = 0.f;
            #pragma unroll
            for (int c = 0; c < 16; ++c) { const float d = v[c]-mu; q += d*d; }
            const float var = q + __shfl_xor(q, 1);
            const float inv = rsqrtf(var * (1.f/32.f) + 1e-5f);
            #pragma unroll
            for (int j = 0; j < 8; ++j) {
                const int c = half*16 + 2*j;
                pk[j] = packh2((v[2*j]   - mu) * inv * n2g[c]   + n2b[c],
                               (v[2*j+1] - mu) * inv * n2g[c+1] + n2b[c+1]);
            }
        } else {
            #pragma unroll
            for (int j = 0; j < 8; ++j) pk[j] = 0u;
        }
        uint4* dst = (uint4*)&u.xnA[px][half * 16];
        dst[0] = *(uint4*)&pk[0];
        dst[1] = *(uint4*)&pk[4];
    } else if (tid < 248) {
        const int t2 = tid - 200;
        const uint4 z = {0u,0u,0u,0u};
        *(uint4*)&u.xnA[100 + (t2 >> 2)][(t2 & 3) * 8] = z;
    }
    __syncthreads();

    // ---- P1: FC1 MFMA (bias in C) -> packed GELU -> hid ----
    {
        const int c0 = wv * 32 + 2 * lm;
        const float bias0 = b1[c0], bias1 = b1[c0 + 1];
        const floatx4 cb0 = {bias0, bias0, bias0, bias0};
        const floatx4 cb1 = {bias1, bias1, bias1, bias1};
        for (int mt = 0; mt < 7; ++mt) {
            const half8v af = *(const half8v*)&u.xnA[mt * 16 + lm][lq * 8];
            floatx4 a0 = __builtin_amdgcn_mfma_f32_16x16x32_f16(af, bf0, cb0, 0, 0, 0);
            floatx4 a1 = __builtin_amdgcn_mfma_f32_16x16x32_f16(af, bf1, cb1, 0, 0, 0);
            #pragma unroll
            for (int r = 0; r < 4; ++r) {
                const int p = mt * 16 + lq * 4 + r;
                if (mt < 6 || p < 100) {
                    half2v hv;
                    hv.x = (_Float16)a0[r];
                    hv.y = (_Float16)a1[r];
                    half2v g = gelu2v(hv);
                    unsigned int bits = __builtin_bit_cast(unsigned int, g);
                    if (edge) {
                        const int hy = (p * 205) >> 11;
                        const int hx = p - hy * 10;
                        const int iy = y0 + hy - 1, ix = x0 + hx - 1;
                        const bool inb = (iy >= 0) & (iy < IMG) & (ix >= 0) & (ix < IMG);
                        if (!inb) bits = 0u;
                    }
                    *(unsigned int*)&hid[p][c0] = bits;
                }
            }
        }
    }
    __syncthreads();

    // ---- P2: dwconv 3x3, row-blocked (3x10 strip in regs) -> glA ----
    {
        const int jq = tid & 31, pg = tid >> 5;
        const int j0 = 4 * jq;
        half2v dwa[9], dwc[9];
        #pragma unroll
        for (int t = 0; t < 9; ++t) {
            dwa[t].x = (_Float16)dw[(j0    ) * 9 + t];
            dwa[t].y = (_Float16)dw[(j0 + 1) * 9 + t];
            dwc[t].x = (_Float16)dw[(j0 + 2) * 9 + t];
            dwc[t].y = (_Float16)dw[(j0 + 3) * 9 + t];
        }
        half2v acca[8], accc[8];
        {
            half2v dba, dbc;
            dba.x = (_Float16)dwb[j0];     dba.y = (_Float16)dwb[j0 + 1];
            dbc.x = (_Float16)dwb[j0 + 2]; dbc.y = (_Float16)dwb[j0 + 3];
            #pragma unroll
            for (int i = 0; i < 8; ++i) { acca[i] = dba; accc[i] = dbc; }
        }
        #pragma unroll
        for (int ky = 0; ky < 3; ++ky) {
            uint2 rr[10];
            #pragma unroll
            for (int cx = 0; cx < 10; ++cx)
                rr[cx] = *(const uint2*)&hid[(pg + ky) * 10 + cx][j0];
            #pragma unroll
            for (int i = 0; i < 8; ++i)
                #pragma unroll
                for (int kx = 0; kx < 3; ++kx) {
                    acca[i] = __builtin_bit_cast(half2v, rr[i + kx].x) * dwa[ky*3+kx] + acca[i];
                    accc[i] = __builtin_bit_cast(half2v, rr[i + kx].y) * dwc[ky*3+kx] + accc[i];
                }
        }
        __syncthreads();          // hid reads done; glA may alias xnA safely
        #pragma unroll
        for (int i = 0; i < 8; ++i) {
            const half2v ga = gelu2v(acca[i]);
            const half2v gc = gelu2v(accc[i]);
            uint2 ow;
            ow.x = __builtin_bit_cast(unsigned int, ga);
            ow.y = __builtin_bit_cast(unsigned int, gc);
            *(uint2*)&u.glA[pg * 8 + i][j0] = ow;
        }
    }
    __syncthreads();

    // ---- P3: FC2 MFMA (K=128, bias in C) + residual -> out ----
    {
        #pragma unroll
        for (int nt = 0; nt < 2; ++nt) {
            const int mt = wv;
            const int c = nt * 16 + lm;
            const float bias = b2[c];
            floatx4 acc = {bias, bias, bias, bias};
            #pragma unroll
            for (int kc = 0; kc < 4; ++kc) {
                const half8v a = *(const half8v*)&u.glA[mt * 16 + lm][kc * 32 + lq * 8];
                acc = __builtin_amdgcn_mfma_f32_16x16x32_f16(a, w2f[nt][kc], acc, 0, 0, 0);
            }
            #pragma unroll
            for (int r = 0; r < 4; ++r) {
                const int p = mt * 16 + lq * 4 + r;
                const int iy = y0 + (p >> 3), ix = x0 + (p & 7);
                const size_t g = ((size_t)b * HWTOK + iy * IMG + ix) * CH + c;
                out[g] = x1[g] + acc[r];
            }
        }
    }
}

// ---------------------------------------------------------------------------
// Kernel 2 (fallback, ws too small): round-10 LeFF with LDS weight staging.
// ---------------------------------------------------------------------------
__global__ __launch_bounds__(256, 3) void leff_kernel_st(
    const float* __restrict__ x1,
    const float* __restrict__ n2g, const float* __restrict__ n2b,
    const float* __restrict__ w1,  const float* __restrict__ b1,
    const float* __restrict__ dw,  const float* __restrict__ dwb,
    const float* __restrict__ w2,  const float* __restrict__ b2,
    float* __restrict__ out)
{
    union SharedU {
        struct { unsigned short xnA[112][40]; unsigned short w1T[128][40]; } p1;
        struct { unsigned short glA[64][136]; unsigned short w2T[32][136]; } p3;
    };
    __shared__ __align__(16) SharedU u;
    __shared__ __align__(16) unsigned short hid[100][132];

    const int blk = blockIdx.x;
    const int b = blk >> 10, tyb = (blk >> 5) & 31, txb = blk & 31;
    const int y0 = tyb * 8, x0 = txb * 8;
    const int tid = threadIdx.x;
    const int wv = tid >> 6;
    const int l  = tid & 63;
    const int lm = l & 15;
    const int lq = l >> 4;
    const bool edge = (tyb == 0) | (tyb == 31) | (txb == 0) | (txb == 31);

    if (tid < 200) {
        const int px = tid >> 1, half = tid & 1;
        const int hy = px / 10, hx = px % 10;
        const int iy = y0 + hy - 1, ix = x0 + hx - 1;
        const bool inb = (iy >= 0 && iy < IMG && ix >= 0 && ix < IMG);
        unsigned int pk[8];
        if (inb) {
            const size_t base = ((size_t)b * HWTOK + iy * IMG + ix) * CH + half * 16;
            const float4* xp = (const float4*)(x1 + base);
            float v[16];
            float s = 0.f;
            #pragma unroll
            for (int i = 0; i < 4; ++i) {
                const float4 t = xp[i];
                v[i*4+0]=t.x; v[i*4+1]=t.y; v[i*4+2]=t.z; v[i*4+3]=t.w;
                s += t.x + t.y + t.z + t.w;
            }
            const float mu = (s + __shfl_xor(s, 1)) * (1.f / 32.f);
            float q = 0.f;
            #pragma unroll
            for (int c = 0; c < 16; ++c) { const float d = v[c]-mu; q += d*d; }
            const float var = q + __shfl_xor(q, 1);
            const float inv = rsqrtf(var * (1.f/32.f) + 1e-5f);
            #pragma unroll
            for (int j = 0; j < 8; ++j) {
                const int c = half*16 + 2*j;
                pk[j] = packh2((v[2*j]   - mu) * inv * n2g[c]   + n2b[c],
                               (v[2*j+1] - mu) * inv * n2g[c+1] + n2b[c+1]);
            }
        } else {
            #pragma unroll
            for (int j = 0; j < 8; ++j) pk[j] = 0u;
        }
        uint4* dst = (uint4*)&u.p1.xnA[px][half * 16];
        dst[0] = *(uint4*)&pk[0];
        dst[1] = *(uint4*)&pk[4];
    } else if (tid < 248) {
        const int t2 = tid - 200;
        const uint4 z = {0u,0u,0u,0u};
        *(uint4*)&u.p1.xnA[100 + (t2 >> 2)][(t2 & 3) * 8] = z;
    }
    #pragma unroll
    for (int i = 0; i < 2; ++i) {
        const int o = tid + i * 256;
        const int row = o & 127, cq = o >> 7;
        const int bl = row >> 5, wi = row & 31;
        const int j = bl * 32 + ((wi & 15) << 1) + (wi >> 4);
        const int k0 = cq * 8;
        unsigned int pk4[4];
        #pragma unroll
        for (int jj = 0; jj < 4; ++jj)
            pk4[jj] = packh2(w1[(k0 + 2*jj) * 128 + j], w1[(k0 + 2*jj + 1) * 128 + j]);
        *(uint4*)&u.p1.w1T[row][k0] = *(uint4*)&pk4[0];
    }
    __syncthreads();

    {
        const int c0 = wv * 32 + 2 * lm;
        const half8v bf0 = *(const half8v*)&u.p1.w1T[wv * 32 + lm][lq * 8];
        const half8v bf1 = *(const half8v*)&u.p1.w1T[wv * 32 + 16 + lm][lq * 8];
        const float bias0 = b1[c0], bias1 = b1[c0 + 1];
        const floatx4 cb0 = {bias0, bias0, bias0, bias0};
        const floatx4 cb1 = {bias1, bias1, bias1, bias1};
        for (int mt = 0; mt < 7; ++mt) {
            const half8v af = *(const half8v*)&u.p1.xnA[mt * 16 + lm][lq * 8];
            floatx4 a0 = __builtin_amdgcn_mfma_f32_16x16x32_f16(af, bf0, cb0, 0, 0, 0);
            floatx4 a1 = __builtin_amdgcn_mfma_f32_16x16x32_f16(af, bf1, cb1, 0, 0, 0);
            #pragma unroll
            for (int r = 0; r < 4; ++r) {
                const int p = mt * 16 + lq * 4 + r;
                if (mt < 6 || p < 100) {
                    half2v hv;
                    hv.x = (_Float16)a0[r];
                    hv.y = (_Float16)a1[r];
                    half2v g = gelu2v(hv);
                    unsigned int bits = __builtin_bit_cast(unsigned int, g);
                    if (edge) {
                        const int hy = (p * 205) >> 11;
                        const int hx = p - hy * 10;
                        const int iy = y0 + hy - 1, ix = x0 + hx - 1;
                        const bool inb = (iy >= 0) & (iy < IMG) & (ix >= 0) & (ix < IMG);
                        if (!inb) bits = 0u;
                    }
                    *(unsigned int*)&hid[p][c0] = bits;
                }
            }
        }
    }
    __syncthreads();

    {
        const int jq = tid & 31, pg = tid >> 5;
        const int j0 = 4 * jq;
        half2v dwa[9], dwc[9];
        #pragma unroll
        for (int t = 0; t < 9; ++t) {
            dwa[t].x = (_Float16)dw[(j0    ) * 9 + t];
            dwa[t].y = (_Float16)dw[(j0 + 1) * 9 + t];
            dwc[t].x = (_Float16)dw[(j0 + 2) * 9 + t];
            dwc[t].y = (_Float16)dw[(j0 + 3) * 9 + t];
        }
        half2v acca[8], accc[8];
        {
            half2v dba, dbc;
            dba.x = (_Float16)dwb[j0];     dba.y = (_Float16)dwb[j0 + 1];
            dbc.x = (_Float16)dwb[j0 + 2]; dbc.y = (_Float16)dwb[j0 + 3];
            #pragma unroll
            for (int i = 0; i < 8; ++i) { acca[i] = dba; accc[i] = dbc; }
        }
        #pragma unroll
        for (int ky = 0; ky < 3; ++ky) {
            uint2 rr[10];
            #pragma unroll
            for (int cx = 0; cx < 10; ++cx)
                rr[cx] = *(const uint2*)&hid[(pg + ky) * 10 + cx][j0];
            #pragma unroll
            for (int i = 0; i < 8; ++i)
                #pragma unroll
                for (int kx = 0; kx < 3; ++kx) {
                    acca[i] = __builtin_bit_cast(half2v, rr[i + kx].x) * dwa[ky*3+kx] + acca[i];
                    accc[i] = __builtin_bit_cast(half2v, rr[i + kx].y) * dwc[ky*3+kx] + accc[i];
                }
        }
        __syncthreads();
        #pragma unroll
        for (int i = 0; i < 8; ++i) {
            const half2v ga = gelu2v(acca[i]);
            const half2v gc = gelu2v(accc[i]);
            uint2 ow;
            ow.x = __builtin_bit_cast(unsigned int, ga);
            ow.y = __builtin_bit_cast(unsigned int, gc);
            *(uint2*)&u.p3.glA[pg * 8 + i][j0] = ow;
        }
        #pragma unroll
        for (int i = 0; i < 2; ++i) {
            const int o = tid + i * 256;
            const int c = o & 31, kq = o >> 5;
            const int k0 = kq * 8;
            unsigned int pk4[4];
            #pragma unroll
            for (int jj = 0; jj < 4; ++jj)
                pk4[jj] = packh2(w2[(k0 + 2*jj) * 32 + c], w2[(k0 + 2*jj + 1) * 32 + c]);
            *(uint4*)&u.p3.w2T[c][k0] = *(uint4*)&pk4[0];
        }
    }
    __syncthreads();

    {
        #pragma unroll
        for (int t = 0; t < 2; ++t) {
            const int idx = 2 * wv + t;
            const int mt = idx >> 1, nt = idx & 1;
            const int c = nt * 16 + lm;
            const float bias = b2[c];
            floatx4 acc = {bias, bias, bias, bias};
            #pragma unroll
            for (int kc = 0; kc < 4; ++kc) {
                const half8v a  = *(const half8v*)&u.p3.glA[mt * 16 + lm][kc * 32 + lq * 8];
                const half8v bb = *(const half8v*)&u.p3.w2T[nt * 16 + lm][kc * 32 + lq * 8];
                acc = __builtin_amdgcn_mfma_f32_16x16x32_f16(a, bb, acc, 0, 0, 0);
            }
            #pragma unroll
            for (int r = 0; r < 4; ++r) {
                const int p = mt * 16 + lq * 4 + r;
                const int iy = y0 + (p >> 3), ix = x0 + (p & 7);
                const size_t g = ((size_t)b * HWTOK + iy * IMG + ix) * CH + c;
                out[g] = x1[g] + acc[r];
            }
        }
    }
}

// ---------------------------------------------------------------------------
extern "C" void kernel_launch(void* const* d_in, const int* in_sizes, int n_in,
                              void* d_out, int out_size, void* d_ws, size_t ws_size,
                              hipStream_t stream)
{
    const float* x    = (const float*)d_in[0];
    const float* n1g  = (const float*)d_in[1];
    const float* n1b  = (const float*)d_in[2];
    const float* wq   = (const float*)d_in[3];
    const float* bq   = (const float*)d_in[4];
    const float* wkv  = (const float*)d_in[5];
    const float* bkv  = (const float*)d_in[6];
    const float* wo   = (const float*)d_in[7];
    const float* bo   = (const float*)d_in[8];
    const float* relb = (const float*)d_in[9];
    const float* n2g  = (const float*)d_in[10];
    const float* n2b  = (const float*)d_in[11];
    const float* w1   = (const float*)d_in[12];
    const float* b1   = (const float*)d_in[13];
    const float* dw   = (const float*)d_in[14];
    const float* dwb  = (const float*)d_in[15];
    const float* w2   = (const float*)d_in[16];
    const float* b2   = (const float*)d_in[17];

    float* out = (float*)d_out;
    float* x1  = (float*)d_ws;                       // 64 MB
    const size_t X1_BYTES = (size_t)8 * HWTOK * CH * 4;
    const size_t W_BYTES  = 2 * 4096 * sizeof(unsigned short);   // w1p + w2p

    const bool gw = ws_size >= X1_BYTES + W_BYTES;

    if (gw) {
        unsigned short* w1p = (unsigned short*)((char*)d_ws + X1_BYTES);
        unsigned short* w2p = w1p + 4096;
        prep_kernel<<<16, 256, 0, stream>>>(w1, w2, w1p, w2p);
        attn_kernel<<<4096, 256, 0, stream>>>(x, n1g, n1b, wq, bq, wkv, bkv,
                                              wo, bo, relb, x1);
        leff_kernel_gw<<<8192, 256, 0, stream>>>(x1, n2g, n2b, b1, dw, dwb,
                                                 b2, w1p, w2p, out);
    } else {
        attn_kernel<<<4096, 256, 0, stream>>>(x, n1g, n1b, wq, bq, wkv, bkv,
                                              wo, bo, relb, x1);
        leff_kernel_st<<<8192, 256, 0, stream>>>(x1, n2g, n2b, w1, b1, dw, dwb,
                                                 w2, b2, out);
    }
}

// Round 12
// 158.812 us; speedup vs baseline: 1.0305x; 1.0305x over previous
//
#include <hip/hip_runtime.h>
#include <hip/hip_bf16.h>
#include <math.h>

// Problem constants (B=8, H=W=256, C=32, WIN=8, HEADS=2, DH=16, HIDDEN=128)
#define IMG   256
#define HWTOK 65536
#define CH    32

typedef __attribute__((ext_vector_type(8))) _Float16 half8v;    // 8 fp16
typedef __attribute__((ext_vector_type(2))) _Float16 half2v;    // 2 fp16
typedef __attribute__((ext_vector_type(4))) float floatx4;

__device__ __forceinline__ unsigned short f2h(float f) {
    _Float16 h = (_Float16)f;
    return __builtin_bit_cast(unsigned short, h);
}
__device__ __forceinline__ float h2f(unsigned short u) {
    return (float)__builtin_bit_cast(_Float16, u);
}
__device__ __forceinline__ unsigned packh2(float a, float b) {
    return (unsigned)f2h(a) | ((unsigned)f2h(b) << 16);
}

// GELU via odd Taylor of Phi(v) = 0.5 + v*p(v^2), packed fp16. (round-10 form)
__device__ __forceinline__ half2v gelu2v(half2v v) {
    const half2v hi = (half2v)(_Float16)( 2.0f);
    const half2v lo = (half2v)(_Float16)(-2.0f);
    const half2v vc = __builtin_elementwise_min(__builtin_elementwise_max(v, lo), hi);
    const half2v s  = vc * vc;
    half2v p = s * (half2v)(_Float16)(-1.18726e-3f) + (half2v)(_Float16)(9.97356e-3f);
    p = s * p + (half2v)(_Float16)(-6.64904e-2f);
    p = s * p + (half2v)(_Float16)( 3.989423e-1f);
    return v * (vc * p + (half2v)(_Float16)(0.5f));
}

// ---------------------------------------------------------------------------
// Kernel 1: LN1 + window attention + proj + residual.
// Grid = 4097: blocks 0..4095 do attention (2 windows each); block 4096 does
// the one-shot fp16 weight marshalling for leff (w1p permuted-transposed,
// w2p transposed) — avoids a separate prep dispatch.
// ---------------------------------------------------------------------------
__global__ __launch_bounds__(256) void attn_kernel(
    const float* __restrict__ x,
    const float* __restrict__ n1g, const float* __restrict__ n1b,
    const float* __restrict__ wq,  const float* __restrict__ bq,
    const float* __restrict__ wkv, const float* __restrict__ bkv,
    const float* __restrict__ wo,  const float* __restrict__ bo,
    const float* __restrict__ relb,
    const float* __restrict__ w1,  const float* __restrict__ w2,
    unsigned short* __restrict__ w1p, unsigned short* __restrict__ w2p,
    float* __restrict__ x1)
{
    // ---- embedded prep block ----
    if (blockIdx.x >= 4096) {
        #pragma unroll
        for (int i = 0; i < 16; ++i) {
            const int t = threadIdx.x + i * 256;          // 0..4095
            const int row = t >> 5, k = t & 31;
            const int bl = row >> 5, wi = row & 31;
            const int j = bl * 32 + ((wi & 15) << 1) + (wi >> 4);   // perm(row)
            w1p[t] = f2h(w1[k * 128 + j]);
            const int n = t >> 7, kk = t & 127;
            w2p[t] = f2h(w2[kk * 32 + n]);
        }
        return;
    }

    struct Win {
        union {
            unsigned short xn[64][40];
            unsigned short P[2][64][72];
            unsigned short O[64][40];
        } u;
        unsigned short Q[64][40];
        unsigned short K[64][56];
        unsigned short VT[2][16][72];
    };
    __shared__ Win W[2];
    __shared__ unsigned short bias16[2][228];
    __shared__ float denom[2][2][64];

    const int tid = threadIdx.x;
    const int wv  = tid >> 6;
    const int w   = wv >> 1;
    const int h   = wv & 1;
    const int l   = tid & 63;
    const int lm  = l & 15, lq = l >> 4;
    Win& S = W[w];

    const int win = blockIdx.x * 2 + w;
    const int b   = win >> 10;
    const int wh  = (win >> 5) & 31, ww = win & 31;
    const size_t wbase = ((size_t)b * HWTOK + (wh * 8) * IMG + ww * 8) * CH;

    const float LOG2E = 1.4426950408889634f;
    const float QSC   = 0.25f * LOG2E;

    half8v bwq, bwk, bwv, bwo0, bwo1;
    {
        const int lq8 = lq * 8;
        #pragma unroll
        for (int i = 0; i < 8; ++i) {
            bwq[i]  = (_Float16)(wq[(lq8 + i) * 32 + h * 16 + lm] * QSC);
            bwk[i]  = (_Float16)wkv[(lq8 + i) * 64 + h * 16 + lm];
            bwv[i]  = (_Float16)wkv[(lq8 + i) * 64 + 32 + h * 16 + lm];
            bwo0[i] = (_Float16)wo [(lq8 + i) * 32 + lm];
            bwo1[i] = (_Float16)wo [(lq8 + i) * 32 + 16 + lm];
        }
    }

    if (tid < 128) {
        const int sw = tid >> 6, st = tid & 63;
        Win& SS = W[sw];
        const int swin = blockIdx.x * 2 + sw;
        const int sb = swin >> 10, swh = (swin >> 5) & 31, sww = swin & 31;
        const size_t sbase = ((size_t)sb * HWTOK
                            + (swh * 8 + (st >> 3)) * IMG + sww * 8 + (st & 7)) * CH;
        const float4* xp = (const float4*)(x + sbase);
        float xr[32];
        float mu = 0.f;
        #pragma unroll
        for (int i = 0; i < 8; ++i) {
            const float4 v = xp[i];
            xr[i*4+0]=v.x; xr[i*4+1]=v.y; xr[i*4+2]=v.z; xr[i*4+3]=v.w;
            mu += v.x + v.y + v.z + v.w;
        }
        mu *= (1.f / 32.f);
        float var = 0.f;
        #pragma unroll
        for (int c = 0; c < 32; ++c) { const float d = xr[c] - mu; var += d * d; }
        const float inv = rsqrtf(var * (1.f / 32.f) + 1e-5f);
        unsigned int pk[16];
        #pragma unroll
        for (int j = 0; j < 16; ++j)
            pk[j] = packh2((xr[2*j]   - mu) * inv * n1g[2*j]   + n1b[2*j],
                           (xr[2*j+1] - mu) * inv * n1g[2*j+1] + n1b[2*j+1]);
        uint4* dst = (uint4*)&SS.u.xn[st][0];
        #pragma unroll
        for (int j = 0; j < 4; ++j) dst[j] = *(uint4*)&pk[j * 4];
        const uint4 z = {0u, 0u, 0u, 0u};
        *(uint4*)&SS.K[st][16] = z;
        *(uint4*)&SS.K[st][24] = z;
    } else {
        const int t2 = tid - 128;
        for (int i = t2; i < 450; i += 128) {
            const int hh = (i >= 225), r = i - hh * 225;
            bias16[hh][r] = f2h(relb[r * 2 + hh] * LOG2E);
        }
    }
    __syncthreads();

    const float bqv = bq[h*16 + lm] * QSC;
    const float bkv_ = bkv[h*16 + lm];
    const float bvv = bkv[32 + h*16 + lm];
    const floatx4 cq = {bqv, bqv, bqv, bqv};
    const floatx4 ck = {bkv_, bkv_, bkv_, bkv_};
    const floatx4 cv = {bvv, bvv, bvv, bvv};
    const floatx4 zero = {0.f, 0.f, 0.f, 0.f};

    #pragma unroll
    for (int mt = 0; mt < 4; ++mt) {
        const half8v a = *(const half8v*)&S.u.xn[mt*16 + lm][lq*8];
        const floatx4 dq = __builtin_amdgcn_mfma_f32_16x16x32_f16(a, bwq, cq, 0,0,0);
        const floatx4 dk = __builtin_amdgcn_mfma_f32_16x16x32_f16(a, bwk, ck, 0,0,0);
        const floatx4 dv = __builtin_amdgcn_mfma_f32_16x16x32_f16(a, bwv, cv, 0,0,0);
        const int r0 = mt*16 + lq*4;
        #pragma unroll
        for (int r = 0; r < 4; ++r) {
            S.Q[r0 + r][h*16 + lm] = f2h(dq[r]);
            S.K[r0 + r][h*32 + lm] = f2h(dk[r]);
        }
        uint2 vv;
        vv.x = packh2(dv[0], dv[1]);
        vv.y = packh2(dv[2], dv[3]);
        *(uint2*)&S.VT[h][lm][r0] = vv;
    }
    __syncthreads();

    half8v ak[4], bqf[4];
    #pragma unroll
    for (int mt = 0; mt < 4; ++mt)
        ak[mt] = *(const half8v*)&S.K[mt*16 + lm][h*16 + lq*8];
    #pragma unroll
    for (int nt = 0; nt < 4; ++nt)
        bqf[nt] = *(const half8v*)&S.Q[nt*16 + lm][lq*8];

    const int cc0 = (lm >> 3) * 15 + (lm & 7);
    const int cml = 15 * (lq >> 1) + 4 * (lq & 1);

    #pragma unroll
    for (int nt = 0; nt < 4; ++nt) {
        float sum = 0.f;
        const int base_nt = 30*nt + cc0 + 112 - cml;
        #pragma unroll
        for (int mt = 0; mt < 4; ++mt) {
            const floatx4 d = __builtin_amdgcn_mfma_f32_16x16x32_f16(ak[mt], bqf[nt], zero, 0,0,0);
            const int ib = base_nt - 30*mt;
            const float e0 = exp2f(d[0] + h2f(bias16[h][ib]));
            const float e1 = exp2f(d[1] + h2f(bias16[h][ib - 1]));
            const float e2 = exp2f(d[2] + h2f(bias16[h][ib - 2]));
            const float e3 = exp2f(d[3] + h2f(bias16[h][ib - 3]));
            sum += (e0 + e1) + (e2 + e3);
            uint2 pw;
            pw.x = packh2(e0, e1);
            pw.y = packh2(e2, e3);
            *(uint2*)&S.u.P[h][nt*16 + lm][mt*16 + lq*4] = pw;
        }
        sum += __shfl_xor(sum, 16);
        sum += __shfl_xor(sum, 32);
        if (l < 16) denom[w][h][nt*16 + l] = __frcp_rn(sum);
    }

    const half8v bva = *(const half8v*)&S.VT[h][lm][lq*8];
    const half8v bvb = *(const half8v*)&S.VT[h][lm][32 + lq*8];
    float oreg[16];
    #pragma unroll
    for (int mt = 0; mt < 4; ++mt) {
        const half8v ap0 = *(const half8v*)&S.u.P[h][mt*16 + lm][lq*8];
        const half8v ap1 = *(const half8v*)&S.u.P[h][mt*16 + lm][32 + lq*8];
        floatx4 ov = __builtin_amdgcn_mfma_f32_16x16x32_f16(ap0, bva, zero, 0,0,0);
        ov         = __builtin_amdgcn_mfma_f32_16x16x32_f16(ap1, bvb, ov,   0,0,0);
        const float4 dn = *(const float4*)&denom[w][h][mt*16 + lq*4];
        oreg[mt*4+0] = ov[0] * dn.x;
        oreg[mt*4+1] = ov[1] * dn.y;
        oreg[mt*4+2] = ov[2] * dn.z;
        oreg[mt*4+3] = ov[3] * dn.w;
    }
    __syncthreads();

    #pragma unroll
    for (int mt = 0; mt < 4; ++mt)
        #pragma unroll
        for (int r = 0; r < 4; ++r)
            S.u.O[mt*16 + lq*4 + r][h*16 + lm] = f2h(oreg[mt*4 + r]);
    __syncthreads();

    const float bo0 = bo[lm], bo1 = bo[16 + lm];
    const floatx4 co0 = {bo0, bo0, bo0, bo0};
    const floatx4 co1 = {bo1, bo1, bo1, bo1};
    #pragma unroll
    for (int mi = 0; mi < 2; ++mi) {
        const int mt = 2*h + mi;
        const half8v aO = *(const half8v*)&S.u.O[mt*16 + lm][lq*8];
        const floatx4 d0 = __builtin_amdgcn_mfma_f32_16x16x32_f16(aO, bwo0, co0, 0,0,0);
        const floatx4 d1 = __builtin_amdgcn_mfma_f32_16x16x32_f16(aO, bwo1, co1, 0,0,0);
        #pragma unroll
        for (int r = 0; r < 4; ++r) {
            const int t = mt*16 + lq*4 + r;
            const size_t g = wbase + (size_t)((t >> 3) * IMG + (t & 7)) * CH;
            x1[g + lm]      = x[g + lm]      + d0[r];
            x1[g + 16 + lm] = x[g + 16 + lm] + d1[r];
        }
    }
}

// ---------------------------------------------------------------------------
// Kernel 2 (primary): fused LeFF, GLOBAL fp16 weights, minimal LDS.
// LDS = union{xnA[112][40] 8.9K, glA[64][132] 16.9K} + hid[100][128] 25.6K
//     = 42,496 B  -> 3 blocks/CU under the 128 KB schedulable-pool hypothesis
// (the decisive test: 43.5 KB and 52.7 KB both gave 2 blocks/CU).
// hid stride 128: FC1 b32 writes 4-way banked (was 2-way), conv b64 ~2-way.
// ---------------------------------------------------------------------------
__global__ __launch_bounds__(256, 3) void leff_kernel_gw(
    const float* __restrict__ x1,
    const float* __restrict__ n2g, const float* __restrict__ n2b,
    const float* __restrict__ b1,
    const float* __restrict__ dw,  const float* __restrict__ dwb,
    const float* __restrict__ b2,
    const unsigned short* __restrict__ w1p,
    const unsigned short* __restrict__ w2p,
    float* __restrict__ out)
{
    union SharedU {
        unsigned short xnA[112][40];    // phase 1 A panel
        unsigned short glA[64][132];    // phase 3 A panel
    };
    __shared__ __align__(16) SharedU u;                     // 16896 B
    __shared__ __align__(16) unsigned short hid[100][128];  // 25600 B

    const int blk = blockIdx.x;
    const int b = blk >> 10, tyb = (blk >> 5) & 31, txb = blk & 31;
    const int y0 = tyb * 8, x0 = txb * 8;
    const int tid = threadIdx.x;
    const int wv = tid >> 6;
    const int l  = tid & 63;
    const int lm = l & 15;
    const int lq = l >> 4;
    const bool edge = (tyb == 0) | (tyb == 31) | (txb == 0) | (txb == 31);

    // ---- hoisted global weight B-frags (L2-hot, independent of LDS) ----
    const half8v bf0 = *(const half8v*)&w1p[(wv * 32 + lm) * 32 + lq * 8];
    const half8v bf1 = *(const half8v*)&w1p[(wv * 32 + 16 + lm) * 32 + lq * 8];
    half8v w2f[2][4];
    #pragma unroll
    for (int nt = 0; nt < 2; ++nt)
        #pragma unroll
        for (int kc = 0; kc < 4; ++kc)
            w2f[nt][kc] = *(const half8v*)&w2p[(nt*16 + lm) * 128 + kc*32 + lq*8];

    // ---- P0: LN2, 2 threads per halo pixel ----
    if (tid < 200) {
        const int px = tid >> 1, half = tid & 1;
        const int hy = px / 10, hx = px % 10;
        const int iy = y0 + hy - 1, ix = x0 + hx - 1;
        const bool inb = (iy >= 0 && iy < IMG && ix >= 0 && ix < IMG);
        unsigned int pk[8];
        if (inb) {
            const size_t base = ((size_t)b * HWTOK + iy * IMG + ix) * CH + half * 16;
            const float4* xp = (const float4*)(x1 + base);
            float v[16];
            float s = 0.f;
            #pragma unroll
            for (int i = 0; i < 4; ++i) {
                const float4 t = xp[i];
                v[i*4+0]=t.x; v[i*4+1]=t.y; v[i*4+2]=t.z; v[i*4+3]=t.w;
                s += t.x + t.y + t.z + t.w;
            }
            const float mu = (s + __shfl_xor(s, 1)) * (1.f / 32.f);
            float q = 0.f;
            #pragma unroll
            for (int c = 0; c < 16; ++c) { const float d = v[c]-mu; q += d*d; }
            const float var = q + __shfl_xor(q, 1);
            const float inv = rsqrtf(var * (1.f/32.f) + 1e-5f);
            #pragma unroll
            for (int j = 0; j < 8; ++j) {
                const int c = half*16 + 2*j;
                pk[j] = packh2((v[2*j]   - mu) * inv * n2g[c]   + n2b[c],
                               (v[2*j+1] - mu) * inv * n2g[c+1] + n2b[c+1]);
            }
        } else {
            #pragma unroll
            for (int j = 0; j < 8; ++j) pk[j] = 0u;
        }
        uint4* dst = (uint4*)&u.xnA[px][half * 16];
        dst[0] = *(uint4*)&pk[0];
        dst[1] = *(uint4*)&pk[4];
    } else if (tid < 248) {
        const int t2 = tid - 200;
        const uint4 z = {0u,0u,0u,0u};
        *(uint4*)&u.xnA[100 + (t2 >> 2)][(t2 & 3) * 8] = z;
    }
    __syncthreads();

    // ---- P1: FC1 MFMA (bias in C) -> packed GELU -> hid ----
    {
        const int c0 = wv * 32 + 2 * lm;
        const float bias0 = b1[c0], bias1 = b1[c0 + 1];
        const floatx4 cb0 = {bias0, bias0, bias0, bias0};
        const floatx4 cb1 = {bias1, bias1, bias1, bias1};
        for (int mt = 0; mt < 7; ++mt) {
            const half8v af = *(const half8v*)&u.xnA[mt * 16 + lm][lq * 8];
            floatx4 a0 = __builtin_amdgcn_mfma_f32_16x16x32_f16(af, bf0, cb0, 0, 0, 0);
            floatx4 a1 = __builtin_amdgcn_mfma_f32_16x16x32_f16(af, bf1, cb1, 0, 0, 0);
            #pragma unroll
            for (int r = 0; r < 4; ++r) {
                const int p = mt * 16 + lq * 4 + r;
                if (mt < 6 || p < 100) {
                    half2v hv;
                    hv.x = (_Float16)a0[r];
                    hv.y = (_Float16)a1[r];
                    half2v g = gelu2v(hv);
                    unsigned int bits = __builtin_bit_cast(unsigned int, g);
                    if (edge) {
                        const int hy = (p * 205) >> 11;
                        const int hx = p - hy * 10;
                        const int iy = y0 + hy - 1, ix = x0 + hx - 1;
                        const bool inb = (iy >= 0) & (iy < IMG) & (ix >= 0) & (ix < IMG);
                        if (!inb) bits = 0u;
                    }
                    *(unsigned int*)&hid[p][c0] = bits;
                }
            }
        }
    }
    __syncthreads();

    // ---- P2: dwconv 3x3, row-blocked (3x10 strip in regs) -> glA ----
    {
        const int jq = tid & 31, pg = tid >> 5;
        const int j0 = 4 * jq;
        half2v dwa[9], dwc[9];
        #pragma unroll
        for (int t = 0; t < 9; ++t) {
            dwa[t].x = (_Float16)dw[(j0    ) * 9 + t];
            dwa[t].y = (_Float16)dw[(j0 + 1) * 9 + t];
            dwc[t].x = (_Float16)dw[(j0 + 2) * 9 + t];
            dwc[t].y = (_Float16)dw[(j0 + 3) * 9 + t];
        }
        half2v acca[8], accc[8];
        {
            half2v dba, dbc;
            dba.x = (_Float16)dwb[j0];     dba.y = (_Float16)dwb[j0 + 1];
            dbc.x = (_Float16)dwb[j0 + 2]; dbc.y = (_Float16)dwb[j0 + 3];
            #pragma unroll
            for (int i = 0; i < 8; ++i) { acca[i] = dba; accc[i] = dbc; }
        }
        #pragma unroll
        for (int ky = 0; ky < 3; ++ky) {
            uint2 rr[10];
            #pragma unroll
            for (int cx = 0; cx < 10; ++cx)
                rr[cx] = *(const uint2*)&hid[(pg + ky) * 10 + cx][j0];
            #pragma unroll
            for (int i = 0; i < 8; ++i)
                #pragma unroll
                for (int kx = 0; kx < 3; ++kx) {
                    acca[i] = __builtin_bit_cast(half2v, rr[i + kx].x) * dwa[ky*3+kx] + acca[i];
                    accc[i] = __builtin_bit_cast(half2v, rr[i + kx].y) * dwc[ky*3+kx] + accc[i];
                }
        }
        __syncthreads();          // hid reads done; glA may alias xnA safely
        #pragma unroll
        for (int i = 0; i < 8; ++i) {
            const half2v ga = gelu2v(acca[i]);
            const half2v gc = gelu2v(accc[i]);
            uint2 ow;
            ow.x = __builtin_bit_cast(unsigned int, ga);
            ow.y = __builtin_bit_cast(unsigned int, gc);
            *(uint2*)&u.glA[pg * 8 + i][j0] = ow;
        }
    }
    __syncthreads();

    // ---- P3: FC2 MFMA (K=128, bias in C) + residual -> out ----
    {
        #pragma unroll
        for (int nt = 0; nt < 2; ++nt) {
            const int mt = wv;
            const int c = nt * 16 + lm;
            const float bias = b2[c];
            floatx4 acc = {bias, bias, bias, bias};
            #pragma unroll
            for (int kc = 0; kc < 4; ++kc) {
                const half8v a = *(const half8v*)&u.glA[mt * 16 + lm][kc * 32 + lq * 8];
                acc = __builtin_amdgcn_mfma_f32_16x16x32_f16(a, w2f[nt][kc], acc, 0, 0, 0);
            }
            #pragma unroll
            for (int r = 0; r < 4; ++r) {
                const int p = mt * 16 + lq * 4 + r;
                const int iy = y0 + (p >> 3), ix = x0 + (p & 7);
                const size_t g = ((size_t)b * HWTOK + iy * IMG + ix) * CH + c;
                out[g] = x1[g] + acc[r];
            }
        }
    }
}

// ---------------------------------------------------------------------------
extern "C" void kernel_launch(void* const* d_in, const int* in_sizes, int n_in,
                              void* d_out, int out_size, void* d_ws, size_t ws_size,
                              hipStream_t stream)
{
    const float* x    = (const float*)d_in[0];
    const float* n1g  = (const float*)d_in[1];
    const float* n1b  = (const float*)d_in[2];
    const float* wq   = (const float*)d_in[3];
    const float* bq   = (const float*)d_in[4];
    const float* wkv  = (const float*)d_in[5];
    const float* bkv  = (const float*)d_in[6];
    const float* wo   = (const float*)d_in[7];
    const float* bo   = (const float*)d_in[8];
    const float* relb = (const float*)d_in[9];
    const float* n2g  = (const float*)d_in[10];
    const float* n2b  = (const float*)d_in[11];
    const float* w1   = (const float*)d_in[12];
    const float* b1   = (const float*)d_in[13];
    const float* dw   = (const float*)d_in[14];
    const float* dwb  = (const float*)d_in[15];
    const float* w2   = (const float*)d_in[16];
    const float* b2   = (const float*)d_in[17];

    float* out = (float*)d_out;
    float* x1  = (float*)d_ws;                       // 64 MB
    const size_t X1_BYTES = (size_t)8 * HWTOK * CH * 4;
    unsigned short* w1p = (unsigned short*)((char*)d_ws + X1_BYTES);
    unsigned short* w2p = w1p + 4096;

    attn_kernel<<<4097, 256, 0, stream>>>(x, n1g, n1b, wq, bq, wkv, bkv,
                                          wo, bo, relb, w1, w2, w1p, w2p, x1);
    leff_kernel_gw<<<8192, 256, 0, stream>>>(x1, n2g, n2b, b1, dw, dwb,
                                             b2, w1p, w2p, out);
}

// Round 13
// 156.471 us; speedup vs baseline: 1.0459x; 1.0150x over previous
//
#include <hip/hip_runtime.h>
#include <hip/hip_bf16.h>
#include <math.h>

// Problem constants (B=8, H=W=256, C=32, WIN=8, HEADS=2, DH=16, HIDDEN=128)
#define IMG   256
#define HWTOK 65536
#define CH    32

typedef __attribute__((ext_vector_type(8))) _Float16 half8v;    // 8 fp16
typedef __attribute__((ext_vector_type(2))) _Float16 half2v;    // 2 fp16
typedef __attribute__((ext_vector_type(4))) float floatx4;

__device__ __forceinline__ unsigned short f2h(float f) {
    _Float16 h = (_Float16)f;
    return __builtin_bit_cast(unsigned short, h);
}
__device__ __forceinline__ float h2f(unsigned short u) {
    return (float)__builtin_bit_cast(_Float16, u);
}
__device__ __forceinline__ unsigned packh2(float a, float b) {
    return (unsigned)f2h(a) | ((unsigned)f2h(b) << 16);
}

// GELU via odd Taylor of Phi(v) = 0.5 + v*p(v^2), packed fp16. (round-10 form)
__device__ __forceinline__ half2v gelu2v(half2v v) {
    const half2v hi = (half2v)(_Float16)( 2.0f);
    const half2v lo = (half2v)(_Float16)(-2.0f);
    const half2v vc = __builtin_elementwise_min(__builtin_elementwise_max(v, lo), hi);
    const half2v s  = vc * vc;
    half2v p = s * (half2v)(_Float16)(-1.18726e-3f) + (half2v)(_Float16)(9.97356e-3f);
    p = s * p + (half2v)(_Float16)(-6.64904e-2f);
    p = s * p + (half2v)(_Float16)( 3.989423e-1f);
    return v * (vc * p + (half2v)(_Float16)(0.5f));
}

// ---------------------------------------------------------------------------
// Kernel 1: LN1 + window attention + proj + residual.
// ONE window per 128-thread block (2 waves; wave = head).  LDS 36.8 KB ->
// 3 blocks/CU under the 128 KB-pool model (was 72.6 KB -> 1 block/CU).
// Grid = 8193: block 8192 does the one-shot fp16 weight marshalling for leff.
// ---------------------------------------------------------------------------
__global__ __launch_bounds__(128) void attn_kernel(
    const float* __restrict__ x,
    const float* __restrict__ n1g, const float* __restrict__ n1b,
    const float* __restrict__ wq,  const float* __restrict__ bq,
    const float* __restrict__ wkv, const float* __restrict__ bkv,
    const float* __restrict__ wo,  const float* __restrict__ bo,
    const float* __restrict__ relb,
    const float* __restrict__ w1,  const float* __restrict__ w2,
    unsigned short* __restrict__ w1p, unsigned short* __restrict__ w2p,
    float* __restrict__ x1)
{
    // ---- embedded prep block ----
    if (blockIdx.x >= 8192) {
        #pragma unroll
        for (int i = 0; i < 32; ++i) {
            const int t = threadIdx.x + i * 128;          // 0..4095
            const int row = t >> 5, k = t & 31;
            const int bl = row >> 5, wi = row & 31;
            const int j = bl * 32 + ((wi & 15) << 1) + (wi >> 4);   // perm(row)
            w1p[t] = f2h(w1[k * 128 + j]);
            const int n = t >> 7, kk = t & 127;
            w2p[t] = f2h(w2[kk * 32 + n]);
        }
        return;
    }

    struct Win {
        union {
            unsigned short xn[64][40];
            unsigned short P[2][64][72];
            unsigned short O[64][40];
        } u;
        unsigned short Q[64][40];
        unsigned short K[64][56];
        unsigned short VT[2][16][72];
    };
    __shared__ Win S;                          // 35328 B
    __shared__ unsigned short bias16[2][228];  // 912 B
    __shared__ float denom[2][64];             // 512 B   -> 36752 B total

    const int tid = threadIdx.x;
    const int h   = tid >> 6;          // wave = head
    const int l   = tid & 63;
    const int lm  = l & 15, lq = l >> 4;

    const int win = blockIdx.x;
    const int b   = win >> 10;
    const int wh  = (win >> 5) & 31, ww = win & 31;
    const size_t wbase = ((size_t)b * HWTOK + (wh * 8) * IMG + ww * 8) * CH;

    const float LOG2E = 1.4426950408889634f;
    const float QSC   = 0.25f * LOG2E;

    // ---- weight B-frags from global (L2-hot); wq pre-scaled by QSC ----
    half8v bwq, bwk, bwv, bwo0, bwo1;
    {
        const int lq8 = lq * 8;
        #pragma unroll
        for (int i = 0; i < 8; ++i) {
            bwq[i]  = (_Float16)(wq[(lq8 + i) * 32 + h * 16 + lm] * QSC);
            bwk[i]  = (_Float16)wkv[(lq8 + i) * 64 + h * 16 + lm];
            bwv[i]  = (_Float16)wkv[(lq8 + i) * 64 + 32 + h * 16 + lm];
            bwo0[i] = (_Float16)wo [(lq8 + i) * 32 + lm];
            bwo1[i] = (_Float16)wo [(lq8 + i) * 32 + 16 + lm];
        }
    }

    // ---- staging: t<64 LN + K-zero (one token each); t>=64 bias table ----
    if (tid < 64) {
        const int st = tid;
        const size_t sbase = wbase + (size_t)((st >> 3) * IMG + (st & 7)) * CH;
        const float4* xp = (const float4*)(x + sbase);
        float xr[32];
        float mu = 0.f;
        #pragma unroll
        for (int i = 0; i < 8; ++i) {
            const float4 v = xp[i];
            xr[i*4+0]=v.x; xr[i*4+1]=v.y; xr[i*4+2]=v.z; xr[i*4+3]=v.w;
            mu += v.x + v.y + v.z + v.w;
        }
        mu *= (1.f / 32.f);
        float var = 0.f;
        #pragma unroll
        for (int c = 0; c < 32; ++c) { const float d = xr[c] - mu; var += d * d; }
        const float inv = rsqrtf(var * (1.f / 32.f) + 1e-5f);
        unsigned int pk[16];
        #pragma unroll
        for (int j = 0; j < 16; ++j)
            pk[j] = packh2((xr[2*j]   - mu) * inv * n1g[2*j]   + n1b[2*j],
                           (xr[2*j+1] - mu) * inv * n1g[2*j+1] + n1b[2*j+1]);
        uint4* dst = (uint4*)&S.u.xn[st][0];
        #pragma unroll
        for (int j = 0; j < 4; ++j) dst[j] = *(uint4*)&pk[j * 4];
        const uint4 z = {0u, 0u, 0u, 0u};
        *(uint4*)&S.K[st][16] = z;
        *(uint4*)&S.K[st][24] = z;
    } else {
        const int t2 = tid - 64;
        for (int i = t2; i < 450; i += 64) {
            const int hh = (i >= 225), r = i - hh * 225;
            bias16[hh][r] = f2h(relb[r * 2 + hh] * LOG2E);
        }
    }
    __syncthreads();                                   // (1) xn/bias ready

    const float bqv = bq[h*16 + lm] * QSC;
    const float bkv_ = bkv[h*16 + lm];
    const float bvv = bkv[32 + h*16 + lm];
    const floatx4 cq = {bqv, bqv, bqv, bqv};
    const floatx4 ck = {bkv_, bkv_, bkv_, bkv_};
    const floatx4 cv = {bvv, bvv, bvv, bvv};
    const floatx4 zero = {0.f, 0.f, 0.f, 0.f};

    // ---- QKV projection (own head) ----
    #pragma unroll
    for (int mt = 0; mt < 4; ++mt) {
        const half8v a = *(const half8v*)&S.u.xn[mt*16 + lm][lq*8];
        const floatx4 dq = __builtin_amdgcn_mfma_f32_16x16x32_f16(a, bwq, cq, 0,0,0);
        const floatx4 dk = __builtin_amdgcn_mfma_f32_16x16x32_f16(a, bwk, ck, 0,0,0);
        const floatx4 dv = __builtin_amdgcn_mfma_f32_16x16x32_f16(a, bwv, cv, 0,0,0);
        const int r0 = mt*16 + lq*4;
        #pragma unroll
        for (int r = 0; r < 4; ++r) {
            S.Q[r0 + r][h*16 + lm] = f2h(dq[r]);
            S.K[r0 + r][h*32 + lm] = f2h(dk[r]);
        }
        uint2 vv;
        vv.x = packh2(dv[0], dv[1]);
        vv.y = packh2(dv[2], dv[3]);
        *(uint2*)&S.VT[h][lm][r0] = vv;
    }
    __syncthreads();                                   // (2) Q needs both heads

    // ---- S^T = mfma(K, Q) ----
    half8v ak[4], bqf[4];
    #pragma unroll
    for (int mt = 0; mt < 4; ++mt)
        ak[mt] = *(const half8v*)&S.K[mt*16 + lm][h*16 + lq*8];
    #pragma unroll
    for (int nt = 0; nt < 4; ++nt)
        bqf[nt] = *(const half8v*)&S.Q[nt*16 + lm][lq*8];

    const int cc0 = (lm >> 3) * 15 + (lm & 7);
    const int cml = 15 * (lq >> 1) + 4 * (lq & 1);

    #pragma unroll
    for (int nt = 0; nt < 4; ++nt) {
        float sum = 0.f;
        const int base_nt = 30*nt + cc0 + 112 - cml;
        #pragma unroll
        for (int mt = 0; mt < 4; ++mt) {
            const floatx4 d = __builtin_amdgcn_mfma_f32_16x16x32_f16(ak[mt], bqf[nt], zero, 0,0,0);
            const int ib = base_nt - 30*mt;
            const float e0 = exp2f(d[0] + h2f(bias16[h][ib]));
            const float e1 = exp2f(d[1] + h2f(bias16[h][ib - 1]));
            const float e2 = exp2f(d[2] + h2f(bias16[h][ib - 2]));
            const float e3 = exp2f(d[3] + h2f(bias16[h][ib - 3]));
            sum += (e0 + e1) + (e2 + e3);
            uint2 pw;
            pw.x = packh2(e0, e1);
            pw.y = packh2(e2, e3);
            *(uint2*)&S.u.P[h][nt*16 + lm][mt*16 + lq*4] = pw;
        }
        sum += __shfl_xor(sum, 16);
        sum += __shfl_xor(sum, 32);
        if (l < 16) denom[h][nt*16 + l] = __frcp_rn(sum);
    }

    // ---- PV + normalize ----
    const half8v bva = *(const half8v*)&S.VT[h][lm][lq*8];
    const half8v bvb = *(const half8v*)&S.VT[h][lm][32 + lq*8];
    float oreg[16];
    #pragma unroll
    for (int mt = 0; mt < 4; ++mt) {
        const half8v ap0 = *(const half8v*)&S.u.P[h][mt*16 + lm][lq*8];
        const half8v ap1 = *(const half8v*)&S.u.P[h][mt*16 + lm][32 + lq*8];
        floatx4 ov = __builtin_amdgcn_mfma_f32_16x16x32_f16(ap0, bva, zero, 0,0,0);
        ov         = __builtin_amdgcn_mfma_f32_16x16x32_f16(ap1, bvb, ov,   0,0,0);
        const float4 dn = *(const float4*)&denom[h][mt*16 + lq*4];
        oreg[mt*4+0] = ov[0] * dn.x;
        oreg[mt*4+1] = ov[1] * dn.y;
        oreg[mt*4+2] = ov[2] * dn.z;
        oreg[mt*4+3] = ov[3] * dn.w;
    }
    __syncthreads();                 // (3) PV reads done before O clobbers P

    #pragma unroll
    for (int mt = 0; mt < 4; ++mt)
        #pragma unroll
        for (int r = 0; r < 4; ++r)
            S.u.O[mt*16 + lq*4 + r][h*16 + lm] = f2h(oreg[mt*4 + r]);
    __syncthreads();                 // (4) O complete

    // ---- out-projection + residual (bias via C-init) ----
    const float bo0 = bo[lm], bo1 = bo[16 + lm];
    const floatx4 co0 = {bo0, bo0, bo0, bo0};
    const floatx4 co1 = {bo1, bo1, bo1, bo1};
    #pragma unroll
    for (int mi = 0; mi < 2; ++mi) {
        const int mt = 2*h + mi;
        const half8v aO = *(const half8v*)&S.u.O[mt*16 + lm][lq*8];
        const floatx4 d0 = __builtin_amdgcn_mfma_f32_16x16x32_f16(aO, bwo0, co0, 0,0,0);
        const floatx4 d1 = __builtin_amdgcn_mfma_f32_16x16x32_f16(aO, bwo1, co1, 0,0,0);
        #pragma unroll
        for (int r = 0; r < 4; ++r) {
            const int t = mt*16 + lq*4 + r;
            const size_t g = wbase + (size_t)((t >> 3) * IMG + (t & 7)) * CH;
            x1[g + lm]      = x[g + lm]      + d0[r];
            x1[g + 16 + lm] = x[g + 16 + lm] + d1[r];
        }
    }
}

// ---------------------------------------------------------------------------
// Kernel 2: fused LeFF, GLOBAL fp16 weights, minimal LDS.
// glA now aliases HID (dead after P2's in-register reads + barrier):
// LDS = xnA[112][40] 8960 + union{hid[100][128] 25600, glA[64][132]} = 34,560 B
// -> 3 blocks/CU = 103.7 KB even under a 128 KB pool with coarse granularity.
// w2 frags loaded just before P3 (short live range).
// ---------------------------------------------------------------------------
__global__ __launch_bounds__(256, 3) void leff_kernel_gw(
    const float* __restrict__ x1,
    const float* __restrict__ n2g, const float* __restrict__ n2b,
    const float* __restrict__ b1,
    const float* __restrict__ dw,  const float* __restrict__ dwb,
    const float* __restrict__ b2,
    const unsigned short* __restrict__ w1p,
    const unsigned short* __restrict__ w2p,
    float* __restrict__ out)
{
    __shared__ __align__(16) unsigned short xnA[112][40];   // 8960 B
    union HG {
        unsigned short hid[100][128];   // 25600 B
        unsigned short glA[64][132];    // 16896 B (fits inside hid region)
    };
    __shared__ __align__(16) HG hg;                         // total 34560 B

    const int blk = blockIdx.x;
    const int b = blk >> 10, tyb = (blk >> 5) & 31, txb = blk & 31;
    const int y0 = tyb * 8, x0 = txb * 8;
    const int tid = threadIdx.x;
    const int wv = tid >> 6;
    const int l  = tid & 63;
    const int lm = l & 15;
    const int lq = l >> 4;
    const bool edge = (tyb == 0) | (tyb == 31) | (txb == 0) | (txb == 31);

    // ---- FC1 weight B-frags (needed in P1) ----
    const half8v bf0 = *(const half8v*)&w1p[(wv * 32 + lm) * 32 + lq * 8];
    const half8v bf1 = *(const half8v*)&w1p[(wv * 32 + 16 + lm) * 32 + lq * 8];

    // ---- P0: LN2, 2 threads per halo pixel ----
    if (tid < 200) {
        const int px = tid >> 1, half = tid & 1;
        const int hy = px / 10, hx = px % 10;
        const int iy = y0 + hy - 1, ix = x0 + hx - 1;
        const bool inb = (iy >= 0 && iy < IMG && ix >= 0 && ix < IMG);
        unsigned int pk[8];
        if (inb) {
            const size_t base = ((size_t)b * HWTOK + iy * IMG + ix) * CH + half * 16;
            const float4* xp = (const float4*)(x1 + base);
            float v[16];
            float s = 0.f;
            #pragma unroll
            for (int i = 0; i < 4; ++i) {
                const float4 t = xp[i];
                v[i*4+0]=t.x; v[i*4+1]=t.y; v[i*4+2]=t.z; v[i*4+3]=t.w;
                s += t.x + t.y + t.z + t.w;
            }
            const float mu = (s + __shfl_xor(s, 1)) * (1.f / 32.f);
            float q = 0.f;
            #pragma unroll
            for (int c = 0; c < 16; ++c) { const float d = v[c]-mu; q += d*d; }
            const float var = q + __shfl_xor(q, 1);
            const float inv = rsqrtf(var * (1.f/32.f) + 1e-5f);
            #pragma unroll
            for (int j = 0; j < 8; ++j) {
                const int c = half*16 + 2*j;
                pk[j] = packh2((v[2*j]   - mu) * inv * n2g[c]   + n2b[c],
                               (v[2*j+1] - mu) * inv * n2g[c+1] + n2b[c+1]);
            }
        } else {
            #pragma unroll
            for (int j = 0; j < 8; ++j) pk[j] = 0u;
        }
        uint4* dst = (uint4*)&xnA[px][half * 16];
        dst[0] = *(uint4*)&pk[0];
        dst[1] = *(uint4*)&pk[4];
    } else if (tid < 248) {
        const int t2 = tid - 200;
        const uint4 z = {0u,0u,0u,0u};
        *(uint4*)&xnA[100 + (t2 >> 2)][(t2 & 3) * 8] = z;
    }
    __syncthreads();

    // ---- P1: FC1 MFMA (bias in C) -> packed GELU -> hid ----
    {
        const int c0 = wv * 32 + 2 * lm;
        const float bias0 = b1[c0], bias1 = b1[c0 + 1];
        const floatx4 cb0 = {bias0, bias0, bias0, bias0};
        const floatx4 cb1 = {bias1, bias1, bias1, bias1};
        for (int mt = 0; mt < 7; ++mt) {
            const half8v af = *(const half8v*)&xnA[mt * 16 + lm][lq * 8];
            floatx4 a0 = __builtin_amdgcn_mfma_f32_16x16x32_f16(af, bf0, cb0, 0, 0, 0);
            floatx4 a1 = __builtin_amdgcn_mfma_f32_16x16x32_f16(af, bf1, cb1, 0, 0, 0);
            #pragma unroll
            for (int r = 0; r < 4; ++r) {
                const int p = mt * 16 + lq * 4 + r;
                if (mt < 6 || p < 100) {
                    half2v hv;
                    hv.x = (_Float16)a0[r];
                    hv.y = (_Float16)a1[r];
                    half2v g = gelu2v(hv);
                    unsigned int bits = __builtin_bit_cast(unsigned int, g);
                    if (edge) {
                        const int hy = (p * 205) >> 11;
                        const int hx = p - hy * 10;
                        const int iy = y0 + hy - 1, ix = x0 + hx - 1;
                        const bool inb = (iy >= 0) & (iy < IMG) & (ix >= 0) & (ix < IMG);
                        if (!inb) bits = 0u;
                    }
                    *(unsigned int*)&hg.hid[p][c0] = bits;
                }
            }
        }
    }
    __syncthreads();

    // ---- P2: dwconv 3x3, row-blocked (3x10 strip in regs) -> glA ----
    {
        const int jq = tid & 31, pg = tid >> 5;
        const int j0 = 4 * jq;
        half2v dwa[9], dwc[9];
        #pragma unroll
        for (int t = 0; t < 9; ++t) {
            dwa[t].x = (_Float16)dw[(j0    ) * 9 + t];
            dwa[t].y = (_Float16)dw[(j0 + 1) * 9 + t];
            dwc[t].x = (_Float16)dw[(j0 + 2) * 9 + t];
            dwc[t].y = (_Float16)dw[(j0 + 3) * 9 + t];
        }
        half2v acca[8], accc[8];
        {
            half2v dba, dbc;
            dba.x = (_Float16)dwb[j0];     dba.y = (_Float16)dwb[j0 + 1];
            dbc.x = (_Float16)dwb[j0 + 2]; dbc.y = (_Float16)dwb[j0 + 3];
            #pragma unroll
            for (int i = 0; i < 8; ++i) { acca[i] = dba; accc[i] = dbc; }
        }
        #pragma unroll
        for (int ky = 0; ky < 3; ++ky) {
            uint2 rr[10];
            #pragma unroll
            for (int cx = 0; cx < 10; ++cx)
                rr[cx] = *(const uint2*)&hg.hid[(pg + ky) * 10 + cx][j0];
            #pragma unroll
            for (int i = 0; i < 8; ++i)
                #pragma unroll
                for (int kx = 0; kx < 3; ++kx) {
                    acca[i] = __builtin_bit_cast(half2v, rr[i + kx].x) * dwa[ky*3+kx] + acca[i];
                    accc[i] = __builtin_bit_cast(half2v, rr[i + kx].y) * dwc[ky*3+kx] + accc[i];
                }
        }
        __syncthreads();          // ALL hid reads complete; glA may alias hid
        #pragma unroll
        for (int i = 0; i < 8; ++i) {
            const half2v ga = gelu2v(acca[i]);
            const half2v gc = gelu2v(accc[i]);
            uint2 ow;
            ow.x = __builtin_bit_cast(unsigned int, ga);
            ow.y = __builtin_bit_cast(unsigned int, gc);
            *(uint2*)&hg.glA[pg * 8 + i][j0] = ow;
        }
    }
    __syncthreads();

    // ---- P3: FC2 MFMA (K=128, bias in C) + residual -> out ----
    {
        half8v w2f[2][4];
        #pragma unroll
        for (int nt = 0; nt < 2; ++nt)
            #pragma unroll
            for (int kc = 0; kc < 4; ++kc)
                w2f[nt][kc] = *(const half8v*)&w2p[(nt*16 + lm) * 128 + kc*32 + lq*8];
        #pragma unroll
        for (int nt = 0; nt < 2; ++nt) {
            const int mt = wv;
            const int c = nt * 16 + lm;
            const float bias = b2[c];
            floatx4 acc = {bias, bias, bias, bias};
            #pragma unroll
            for (int kc = 0; kc < 4; ++kc) {
                const half8v a = *(const half8v*)&hg.glA[mt * 16 + lm][kc * 32 + lq * 8];
                acc = __builtin_amdgcn_mfma_f32_16x16x32_f16(a, w2f[nt][kc], acc, 0, 0, 0);
            }
            #pragma unroll
            for (int r = 0; r < 4; ++r) {
                const int p = mt * 16 + lq * 4 + r;
                const int iy = y0 + (p >> 3), ix = x0 + (p & 7);
                const size_t g = ((size_t)b * HWTOK + iy * IMG + ix) * CH + c;
                out[g] = x1[g] + acc[r];
            }
        }
    }
}

// ---------------------------------------------------------------------------
extern "C" void kernel_launch(void* const* d_in, const int* in_sizes, int n_in,
                              void* d_out, int out_size, void* d_ws, size_t ws_size,
                              hipStream_t stream)
{
    const float* x    = (const float*)d_in[0];
    const float* n1g  = (const float*)d_in[1];
    const float* n1b  = (const float*)d_in[2];
    const float* wq   = (const float*)d_in[3];
    const float* bq   = (const float*)d_in[4];
    const float* wkv  = (const float*)d_in[5];
    const float* bkv  = (const float*)d_in[6];
    const float* wo   = (const float*)d_in[7];
    const float* bo   = (const float*)d_in[8];
    const float* relb = (const float*)d_in[9];
    const float* n2g  = (const float*)d_in[10];
    const float* n2b  = (const float*)d_in[11];
    const float* w1   = (const float*)d_in[12];
    const float* b1   = (const float*)d_in[13];
    const float* dw   = (const float*)d_in[14];
    const float* dwb  = (const float*)d_in[15];
    const float* w2   = (const float*)d_in[16];
    const float* b2   = (const float*)d_in[17];

    float* out = (float*)d_out;
    float* x1  = (float*)d_ws;                       // 64 MB
    const size_t X1_BYTES = (size_t)8 * HWTOK * CH * 4;
    unsigned short* w1p = (unsigned short*)((char*)d_ws + X1_BYTES);
    unsigned short* w2p = w1p + 4096;

    attn_kernel<<<8193, 128, 0, stream>>>(x, n1g, n1b, wq, bq, wkv, bkv,
                                          wo, bo, relb, w1, w2, w1p, w2p, x1);
    leff_kernel_gw<<<8192, 256, 0, stream>>>(x1, n2g, n2b, b1, dw, dwb,
                                             b2, w1p, w2p, out);
}

// Round 15
// 140.325 us; speedup vs baseline: 1.1662x; 1.1151x over previous
//
#include <hip/hip_runtime.h>
#include <hip/hip_bf16.h>
#include <math.h>

// Problem constants (B=8, H=W=256, C=32, WIN=8, HEADS=2, DH=16, HIDDEN=128)
#define IMG   256
#define HWTOK 65536
#define CH    32

typedef __attribute__((ext_vector_type(8))) _Float16 half8v;    // 8 fp16
typedef __attribute__((ext_vector_type(2))) _Float16 half2v;    // 2 fp16
typedef __attribute__((ext_vector_type(4))) float floatx4;

__device__ __forceinline__ unsigned short f2h(float f) {
    _Float16 h = (_Float16)f;
    return __builtin_bit_cast(unsigned short, h);
}
// v_cvt_pkrtz_f16_f32 returns __fp16x2 — bit-cast to our half2v type.
__device__ __forceinline__ half2v pkrtz(float a, float b) {
    return __builtin_bit_cast(half2v, __builtin_amdgcn_cvt_pkrtz(a, b));
}
__device__ __forceinline__ unsigned packh2(float a, float b) {
    return __builtin_bit_cast(unsigned, __builtin_amdgcn_cvt_pkrtz(a, b));
}

// GELU via odd Taylor of Phi(v) = 0.5 + v*p(v^2), packed fp16.
__device__ __forceinline__ half2v gelu2v(half2v v) {
    const half2v hi = (half2v)(_Float16)( 2.0f);
    const half2v lo = (half2v)(_Float16)(-2.0f);
    const half2v vc = __builtin_elementwise_min(__builtin_elementwise_max(v, lo), hi);
    const half2v s  = vc * vc;
    half2v p = s * (half2v)(_Float16)(-1.18726e-3f) + (half2v)(_Float16)(9.97356e-3f);
    p = s * p + (half2v)(_Float16)(-6.64904e-2f);
    p = s * p + (half2v)(_Float16)( 3.989423e-1f);
    return v * (vc * p + (half2v)(_Float16)(0.5f));
}

// ---------------------------------------------------------------------------
// Prep: one-shot marshalling into workspace (29 blocks x 256).
//   bid 0..15 : w1p (permuted-transposed fp16) + w2p (transposed fp16)
//   bid 16..19: wqp (x QSC) / wkp / wvp / wop — fp16 B-frag layout
//   bid 20..27: biasf — rel_bias expanded to f32 MFMA C-fragments
//               [h][nt][mt][lane] float4 (q = nt*16+(l&15), m = mt*16+(l>>4)*4+r)
//   bid 28    : dwp [9][128] fp16 + dwbp [128] fp16
// ---------------------------------------------------------------------------
__global__ __launch_bounds__(256) void prep_kernel(
    const float* __restrict__ w1, const float* __restrict__ w2,
    const float* __restrict__ wq, const float* __restrict__ wkv,
    const float* __restrict__ wo, const float* __restrict__ dw,
    const float* __restrict__ dwb, const float* __restrict__ relb,
    unsigned short* __restrict__ w1p, unsigned short* __restrict__ w2p,
    unsigned short* __restrict__ wqp, unsigned short* __restrict__ wkp,
    unsigned short* __restrict__ wvp, unsigned short* __restrict__ wop,
    unsigned short* __restrict__ dwp, unsigned short* __restrict__ dwbp,
    float* __restrict__ biasf)
{
    const float LOG2E = 1.4426950408889634f;
    const float QSC   = 0.25f * LOG2E;
    const int bid = blockIdx.x, tid = threadIdx.x;

    if (bid < 16) {                       // leff FC weights
        const int t = bid * 256 + tid;    // 0..4095
        const int row = t >> 5, k = t & 31;
        const int bl = row >> 5, wi = row & 31;
        const int j = bl * 32 + ((wi & 15) << 1) + (wi >> 4);   // perm(row)
        w1p[t] = f2h(w1[k * 128 + j]);
        const int n = t >> 7, kk = t & 127;
        w2p[t] = f2h(w2[kk * 32 + n]);
    } else if (bid < 20) {                // attn weights, frag layout
        const int u = (bid - 16) * 256 + tid;      // 0..1023
        const int h = u >> 9, rem = u & 511;
        const int col = rem >> 5, k = rem & 31;    // wqp/wkp/wvp: [h][col16][k32]
        wqp[u] = f2h(wq [k * 32 + h * 16 + col] * QSC);
        wkp[u] = f2h(wkv[k * 64 + h * 16 + col]);
        wvp[u] = f2h(wkv[k * 64 + 32 + h * 16 + col]);
        const int n = u >> 5, kk2 = u & 31;        // wop: [n32][k32]
        wop[u] = f2h(wo[kk2 * 32 + n]);
    } else if (bid < 28) {                // bias C-fragment table
        const int g = (bid - 20) * 256 + tid;      // 0..2047 (float4 index)
        const int h = g >> 10, nt = (g >> 8) & 3, mt = (g >> 6) & 3, l = g & 63;
        const int q = nt * 16 + (l & 15);
        const int mb = mt * 16 + (l >> 4) * 4;
        const int qy = q >> 3, qx = q & 7;
        #pragma unroll
        for (int r = 0; r < 4; ++r) {
            const int m = mb + r;
            const int my = m >> 3, mx = m & 7;
            const int idx = (qy - my + 7) * 15 + (qx - mx + 7);
            biasf[g * 4 + r] = relb[idx * 2 + h] * LOG2E;
        }
    } else {                              // dw pack
        for (int e = tid; e < 1280; e += 256) {
            if (e < 1152) dwp[e] = f2h(dw[(e & 127) * 9 + (e >> 7)]);
            else          dwbp[e - 1152] = f2h(dwb[e - 1152]);
        }
    }
}

// ---------------------------------------------------------------------------
// Kernel 1: LN1 + window attention + proj + residual.
// ONE window per 128-thread block (2 waves; wave = head).
// All weights/bias from prepped fp16/f32 tables (L2-hot).  rel_bias folded
// into MFMA C-init.  LDS = 34,816 B (the proven 3-blocks/CU footprint).
// ---------------------------------------------------------------------------
__global__ __launch_bounds__(128) void attn_kernel(
    const float* __restrict__ x,
    const float* __restrict__ n1g, const float* __restrict__ n1b,
    const float* __restrict__ bq,  const float* __restrict__ bkv,
    const float* __restrict__ bo,
    const unsigned short* __restrict__ wqp,
    const unsigned short* __restrict__ wkp,
    const unsigned short* __restrict__ wvp,
    const unsigned short* __restrict__ wop,
    const float4* __restrict__ biasf4,
    float* __restrict__ x1)
{
    struct Win {
        union {
            unsigned short xn[64][40];    // 5120
            unsigned short P[2][64][72];  // 18432 (max member)
            unsigned short O[64][40];
        } u;
        unsigned short Q[64][40];         // 5120
        unsigned short K[64][48];         // 6144 (cols 16..31 zero mask)
        unsigned short VT[2][16][72];     // 4608
    };
    __shared__ Win S;                     // 34304
    __shared__ float denom[2][64];        // 512  -> 34816 B total

    const int tid = threadIdx.x;
    const int h   = tid >> 6;             // wave = head
    const int l   = tid & 63;
    const int lm  = l & 15, lq = l >> 4;

    const int win = blockIdx.x;
    const int b   = win >> 10;
    const int wh  = (win >> 5) & 31, ww = win & 31;
    const size_t wbase = ((size_t)b * HWTOK + (wh * 8) * IMG + ww * 8) * CH;

    const float LOG2E = 1.4426950408889634f;
    const float QSC   = 0.25f * LOG2E;

    // ---- weight B-frags: single b128 loads from prepped tables ----
    const half8v bwq  = *(const half8v*)&wqp[h * 512 + lm * 32 + lq * 8];
    const half8v bwk  = *(const half8v*)&wkp[h * 512 + lm * 32 + lq * 8];
    const half8v bwv  = *(const half8v*)&wvp[h * 512 + lm * 32 + lq * 8];
    const half8v bwo0 = *(const half8v*)&wop[lm * 32 + lq * 8];
    const half8v bwo1 = *(const half8v*)&wop[(16 + lm) * 32 + lq * 8];

    // ---- LN staging: 2 threads per token (16 ch each, shfl pair-reduce) ----
    {
        const int tok = tid >> 1, half = tid & 1;
        const size_t sbase = wbase
            + (size_t)((tok >> 3) * IMG + (tok & 7)) * CH + half * 16;
        const float4* xp = (const float4*)(x + sbase);
        float v[16];
        float s = 0.f;
        #pragma unroll
        for (int i = 0; i < 4; ++i) {
            const float4 t = xp[i];
            v[i*4+0]=t.x; v[i*4+1]=t.y; v[i*4+2]=t.z; v[i*4+3]=t.w;
            s += t.x + t.y + t.z + t.w;
        }
        const float mu = (s + __shfl_xor(s, 1)) * (1.f / 32.f);
        float qq = 0.f;
        #pragma unroll
        for (int c = 0; c < 16; ++c) { const float d = v[c] - mu; qq += d * d; }
        const float var = qq + __shfl_xor(qq, 1);
        const float inv = rsqrtf(var * (1.f / 32.f) + 1e-5f);
        unsigned pk[8];
        #pragma unroll
        for (int j = 0; j < 8; ++j) {
            const int c = half * 16 + 2 * j;
            pk[j] = packh2((v[2*j]   - mu) * inv * n1g[c]   + n1b[c],
                           (v[2*j+1] - mu) * inv * n1g[c+1] + n1b[c+1]);
        }
        uint4* dst = (uint4*)&S.u.xn[tok][half * 16];
        dst[0] = *(uint4*)&pk[0];
        dst[1] = *(uint4*)&pk[4];
        const uint4 z = {0u, 0u, 0u, 0u};          // zero K mask cols 16..31
        *(uint4*)&S.K[tok][16 + half * 8] = z;
    }
    __syncthreads();                               // (1) xn ready

    const float bqv = bq[h*16 + lm] * QSC;
    const float bkv_ = bkv[h*16 + lm];
    const float bvv = bkv[32 + h*16 + lm];
    const floatx4 cq = {bqv, bqv, bqv, bqv};
    const floatx4 ck = {bkv_, bkv_, bkv_, bkv_};
    const floatx4 cv = {bvv, bvv, bvv, bvv};
    const floatx4 zero = {0.f, 0.f, 0.f, 0.f};

    // ---- QKV projection (own head) ----
    #pragma unroll
    for (int mt = 0; mt < 4; ++mt) {
        const half8v a = *(const half8v*)&S.u.xn[mt*16 + lm][lq*8];
        const floatx4 dq = __builtin_amdgcn_mfma_f32_16x16x32_f16(a, bwq, cq, 0,0,0);
        const floatx4 dk = __builtin_amdgcn_mfma_f32_16x16x32_f16(a, bwk, ck, 0,0,0);
        const floatx4 dv = __builtin_amdgcn_mfma_f32_16x16x32_f16(a, bwv, cv, 0,0,0);
        const int r0 = mt*16 + lq*4;
        #pragma unroll
        for (int r = 0; r < 4; ++r) {
            S.Q[r0 + r][h*16 + lm] = f2h(dq[r]);
            S.K[r0 + r][h*32 + lm] = f2h(dk[r]);   // head h dims at cols 32h
        }
        uint2 vv;
        vv.x = packh2(dv[0], dv[1]);
        vv.y = packh2(dv[2], dv[3]);
        *(uint2*)&S.VT[h][lm][r0] = vv;            // V^T[dim][token]
    }
    __syncthreads();                               // (2) Q needs both heads

    // ---- S^T = mfma(K, Q) with rel_bias as MFMA C-init ----
    half8v ak[4], bqf[4];
    #pragma unroll
    for (int mt = 0; mt < 4; ++mt)
        ak[mt] = *(const half8v*)&S.K[mt*16 + lm][h*16 + lq*8];
    #pragma unroll
    for (int nt = 0; nt < 4; ++nt)
        bqf[nt] = *(const half8v*)&S.Q[nt*16 + lm][lq*8];

    #pragma unroll
    for (int nt = 0; nt < 4; ++nt) {
        float sum = 0.f;
        #pragma unroll
        for (int mt = 0; mt < 4; ++mt) {
            const float4 cb = biasf4[(h*16 + nt*4 + mt) * 64 + l];
            const floatx4 C = {cb.x, cb.y, cb.z, cb.w};
            const floatx4 d = __builtin_amdgcn_mfma_f32_16x16x32_f16(ak[mt], bqf[nt], C, 0,0,0);
            const float e0 = exp2f(d[0]);
            const float e1 = exp2f(d[1]);
            const float e2 = exp2f(d[2]);
            const float e3 = exp2f(d[3]);
            sum += (e0 + e1) + (e2 + e3);
            uint2 pw;
            pw.x = packh2(e0, e1);
            pw.y = packh2(e2, e3);
            *(uint2*)&S.u.P[h][nt*16 + lm][mt*16 + lq*4] = pw;
        }
        sum += __shfl_xor(sum, 16);
        sum += __shfl_xor(sum, 32);
        if (l < 16) denom[h][nt*16 + l] = __frcp_rn(sum);
    }

    // ---- PV + normalize ----
    const half8v bva = *(const half8v*)&S.VT[h][lm][lq*8];
    const half8v bvb = *(const half8v*)&S.VT[h][lm][32 + lq*8];
    float oreg[16];
    #pragma unroll
    for (int mt = 0; mt < 4; ++mt) {
        const half8v ap0 = *(const half8v*)&S.u.P[h][mt*16 + lm][lq*8];
        const half8v ap1 = *(const half8v*)&S.u.P[h][mt*16 + lm][32 + lq*8];
        floatx4 ov = __builtin_amdgcn_mfma_f32_16x16x32_f16(ap0, bva, zero, 0,0,0);
        ov         = __builtin_amdgcn_mfma_f32_16x16x32_f16(ap1, bvb, ov,   0,0,0);
        const float4 dn = *(const float4*)&denom[h][mt*16 + lq*4];
        oreg[mt*4+0] = ov[0] * dn.x;
        oreg[mt*4+1] = ov[1] * dn.y;
        oreg[mt*4+2] = ov[2] * dn.z;
        oreg[mt*4+3] = ov[3] * dn.w;
    }
    __syncthreads();                 // (3) PV reads done before O clobbers P

    #pragma unroll
    for (int mt = 0; mt < 4; ++mt)
        #pragma unroll
        for (int r = 0; r < 4; ++r)
            S.u.O[mt*16 + lq*4 + r][h*16 + lm] = f2h(oreg[mt*4 + r]);
    __syncthreads();                 // (4) O complete

    // ---- out-projection + residual (bias via C-init) ----
    const float bo0 = bo[lm], bo1 = bo[16 + lm];
    const floatx4 co0 = {bo0, bo0, bo0, bo0};
    const floatx4 co1 = {bo1, bo1, bo1, bo1};
    #pragma unroll
    for (int mi = 0; mi < 2; ++mi) {
        const int mt = 2*h + mi;
        const half8v aO = *(const half8v*)&S.u.O[mt*16 + lm][lq*8];
        const floatx4 d0 = __builtin_amdgcn_mfma_f32_16x16x32_f16(aO, bwo0, co0, 0,0,0);
        const floatx4 d1 = __builtin_amdgcn_mfma_f32_16x16x32_f16(aO, bwo1, co1, 0,0,0);
        #pragma unroll
        for (int r = 0; r < 4; ++r) {
            const int t = mt*16 + lq*4 + r;
            const size_t g = wbase + (size_t)((t >> 3) * IMG + (t & 7)) * CH;
            x1[g + lm]      = x[g + lm]      + d0[r];
            x1[g + 16 + lm] = x[g + 16 + lm] + d1[r];
        }
    }
}

// ---------------------------------------------------------------------------
// Kernel 2: fused LeFF, GLOBAL fp16 weights (incl. prepped dw), minimal LDS.
// LDS = xnA 8960 + union{hid[100][128] 25600, glA[64][132]} = 34,560 B
// -> 3 blocks/CU (proven round 13: occupancy 36.9%).
// ---------------------------------------------------------------------------
__global__ __launch_bounds__(256, 3) void leff_kernel_gw(
    const float* __restrict__ x1,
    const float* __restrict__ n2g, const float* __restrict__ n2b,
    const float* __restrict__ b1,  const float* __restrict__ b2,
    const unsigned short* __restrict__ w1p,
    const unsigned short* __restrict__ w2p,
    const unsigned short* __restrict__ dwp,
    const unsigned short* __restrict__ dwbp,
    float* __restrict__ out)
{
    __shared__ __align__(16) unsigned short xnA[112][40];   // 8960 B
    union HG {
        unsigned short hid[100][128];   // 25600 B
        unsigned short glA[64][132];    // 16896 B (fits inside hid region)
    };
    __shared__ __align__(16) HG hg;                         // total 34560 B

    const int blk = blockIdx.x;
    const int b = blk >> 10, tyb = (blk >> 5) & 31, txb = blk & 31;
    const int y0 = tyb * 8, x0 = txb * 8;
    const int tid = threadIdx.x;
    const int wv = tid >> 6;
    const int l  = tid & 63;
    const int lm = l & 15;
    const int lq = l >> 4;
    const bool edge = (tyb == 0) | (tyb == 31) | (txb == 0) | (txb == 31);

    // ---- FC1 weight B-frags (needed in P1) ----
    const half8v bf0 = *(const half8v*)&w1p[(wv * 32 + lm) * 32 + lq * 8];
    const half8v bf1 = *(const half8v*)&w1p[(wv * 32 + 16 + lm) * 32 + lq * 8];

    // ---- P0: LN2, 2 threads per halo pixel ----
    if (tid < 200) {
        const int px = tid >> 1, half = tid & 1;
        const int hy = px / 10, hx = px % 10;
        const int iy = y0 + hy - 1, ix = x0 + hx - 1;
        const bool inb = (iy >= 0 && iy < IMG && ix >= 0 && ix < IMG);
        unsigned int pk[8];
        if (inb) {
            const size_t base = ((size_t)b * HWTOK + iy * IMG + ix) * CH + half * 16;
            const float4* xp = (const float4*)(x1 + base);
            float v[16];
            float s = 0.f;
            #pragma unroll
            for (int i = 0; i < 4; ++i) {
                const float4 t = xp[i];
                v[i*4+0]=t.x; v[i*4+1]=t.y; v[i*4+2]=t.z; v[i*4+3]=t.w;
                s += t.x + t.y + t.z + t.w;
            }
            const float mu = (s + __shfl_xor(s, 1)) * (1.f / 32.f);
            float q = 0.f;
            #pragma unroll
            for (int c = 0; c < 16; ++c) { const float d = v[c]-mu; q += d*d; }
            const float var = q + __shfl_xor(q, 1);
            const float inv = rsqrtf(var * (1.f/32.f) + 1e-5f);
            #pragma unroll
            for (int j = 0; j < 8; ++j) {
                const int c = half*16 + 2*j;
                pk[j] = packh2((v[2*j]   - mu) * inv * n2g[c]   + n2b[c],
                               (v[2*j+1] - mu) * inv * n2g[c+1] + n2b[c+1]);
            }
        } else {
            #pragma unroll
            for (int j = 0; j < 8; ++j) pk[j] = 0u;
        }
        uint4* dst = (uint4*)&xnA[px][half * 16];
        dst[0] = *(uint4*)&pk[0];
        dst[1] = *(uint4*)&pk[4];
    } else if (tid < 248) {
        const int t2 = tid - 200;
        const uint4 z = {0u,0u,0u,0u};
        *(uint4*)&xnA[100 + (t2 >> 2)][(t2 & 3) * 8] = z;
    }
    __syncthreads();

    // ---- P1: FC1 MFMA (bias in C) -> packed GELU -> hid ----
    {
        const int c0 = wv * 32 + 2 * lm;
        const float bias0 = b1[c0], bias1 = b1[c0 + 1];
        const floatx4 cb0 = {bias0, bias0, bias0, bias0};
        const floatx4 cb1 = {bias1, bias1, bias1, bias1};
        for (int mt = 0; mt < 7; ++mt) {
            const half8v af = *(const half8v*)&xnA[mt * 16 + lm][lq * 8];
            floatx4 a0 = __builtin_amdgcn_mfma_f32_16x16x32_f16(af, bf0, cb0, 0, 0, 0);
            floatx4 a1 = __builtin_amdgcn_mfma_f32_16x16x32_f16(af, bf1, cb1, 0, 0, 0);
            #pragma unroll
            for (int r = 0; r < 4; ++r) {
                const int p = mt * 16 + lq * 4 + r;
                if (mt < 6 || p < 100) {
                    half2v g = gelu2v(pkrtz(a0[r], a1[r]));
                    unsigned int bits = __builtin_bit_cast(unsigned int, g);
                    if (edge) {
                        const int hy = (p * 205) >> 11;
                        const int hx = p - hy * 10;
                        const int iy = y0 + hy - 1, ix = x0 + hx - 1;
                        const bool inb = (iy >= 0) & (iy < IMG) & (ix >= 0) & (ix < IMG);
                        if (!inb) bits = 0u;
                    }
                    *(unsigned int*)&hg.hid[p][c0] = bits;
                }
            }
        }
    }
    __syncthreads();

    // ---- P2: dwconv 3x3, row-blocked (3x10 strip in regs) -> glA ----
    {
        const int jq = tid & 31, pg = tid >> 5;
        const int j0 = 4 * jq;
        half2v dwa[9], dwc[9];
        #pragma unroll
        for (int t = 0; t < 9; ++t) {
            const uint2 wp = *(const uint2*)&dwp[t * 128 + j0];
            dwa[t] = __builtin_bit_cast(half2v, wp.x);
            dwc[t] = __builtin_bit_cast(half2v, wp.y);
        }
        half2v acca[8], accc[8];
        {
            const uint2 bp = *(const uint2*)&dwbp[j0];
            const half2v dba = __builtin_bit_cast(half2v, bp.x);
            const half2v dbc = __builtin_bit_cast(half2v, bp.y);
            #pragma unroll
            for (int i = 0; i < 8; ++i) { acca[i] = dba; accc[i] = dbc; }
        }
        #pragma unroll
        for (int ky = 0; ky < 3; ++ky) {
            uint2 rr[10];
            #pragma unroll
            for (int cx = 0; cx < 10; ++cx)
                rr[cx] = *(const uint2*)&hg.hid[(pg + ky) * 10 + cx][j0];
            #pragma unroll
            for (int i = 0; i < 8; ++i)
                #pragma unroll
                for (int kx = 0; kx < 3; ++kx) {
                    acca[i] = __builtin_bit_cast(half2v, rr[i + kx].x) * dwa[ky*3+kx] + acca[i];
                    accc[i] = __builtin_bit_cast(half2v, rr[i + kx].y) * dwc[ky*3+kx] + accc[i];
                }
        }
        __syncthreads();          // ALL hid reads complete; glA may alias hid
        #pragma unroll
        for (int i = 0; i < 8; ++i) {
            const half2v ga = gelu2v(acca[i]);
            const half2v gc = gelu2v(accc[i]);
            uint2 ow;
            ow.x = __builtin_bit_cast(unsigned int, ga);
            ow.y = __builtin_bit_cast(unsigned int, gc);
            *(uint2*)&hg.glA[pg * 8 + i][j0] = ow;
        }
    }
    __syncthreads();

    // ---- P3: FC2 MFMA (K=128, bias in C) + residual -> out ----
    {
        half8v w2f[2][4];
        #pragma unroll
        for (int nt = 0; nt < 2; ++nt)
            #pragma unroll
            for (int kc = 0; kc < 4; ++kc)
                w2f[nt][kc] = *(const half8v*)&w2p[(nt*16 + lm) * 128 + kc*32 + lq*8];
        #pragma unroll
        for (int nt = 0; nt < 2; ++nt) {
            const int mt = wv;
            const int c = nt * 16 + lm;
            const float bias = b2[c];
            floatx4 acc = {bias, bias, bias, bias};
            #pragma unroll
            for (int kc = 0; kc < 4; ++kc) {
                const half8v a = *(const half8v*)&hg.glA[mt * 16 + lm][kc * 32 + lq * 8];
                acc = __builtin_amdgcn_mfma_f32_16x16x32_f16(a, w2f[nt][kc], acc, 0, 0, 0);
            }
            #pragma unroll
            for (int r = 0; r < 4; ++r) {
                const int p = mt * 16 + lq * 4 + r;
                const int iy = y0 + (p >> 3), ix = x0 + (p & 7);
                const size_t g = ((size_t)b * HWTOK + iy * IMG + ix) * CH + c;
                out[g] = x1[g] + acc[r];
            }
        }
    }
}

// ---------------------------------------------------------------------------
extern "C" void kernel_launch(void* const* d_in, const int* in_sizes, int n_in,
                              void* d_out, int out_size, void* d_ws, size_t ws_size,
                              hipStream_t stream)
{
    const float* x    = (const float*)d_in[0];
    const float* n1g  = (const float*)d_in[1];
    const float* n1b  = (const float*)d_in[2];
    const float* wq   = (const float*)d_in[3];
    const float* bq   = (const float*)d_in[4];
    const float* wkv  = (const float*)d_in[5];
    const float* bkv  = (const float*)d_in[6];
    const float* wo   = (const float*)d_in[7];
    const float* bo   = (const float*)d_in[8];
    const float* relb = (const float*)d_in[9];
    const float* n2g  = (const float*)d_in[10];
    const float* n2b  = (const float*)d_in[11];
    const float* w1   = (const float*)d_in[12];
    const float* b1   = (const float*)d_in[13];
    const float* dw   = (const float*)d_in[14];
    const float* dwb  = (const float*)d_in[15];
    const float* w2   = (const float*)d_in[16];
    const float* b2   = (const float*)d_in[17];

    float* out = (float*)d_out;
    float* x1  = (float*)d_ws;                       // 64 MB
    char* base = (char*)d_ws + (size_t)8 * HWTOK * CH * 4;
    unsigned short* w1p  = (unsigned short*)(base);           // 8192 B
    unsigned short* w2p  = (unsigned short*)(base + 8192);    // 8192 B
    unsigned short* wqp  = (unsigned short*)(base + 16384);   // 2048 B
    unsigned short* wkp  = (unsigned short*)(base + 18432);   // 2048 B
    unsigned short* wvp  = (unsigned short*)(base + 20480);   // 2048 B
    unsigned short* wop  = (unsigned short*)(base + 22528);   // 2048 B
    unsigned short* dwp  = (unsigned short*)(base + 24576);   // 2304 B
    unsigned short* dwbp = (unsigned short*)(base + 26880);   // 256 B
    float*          bias = (float*)(base + 28672);            // 32768 B

    prep_kernel<<<29, 256, 0, stream>>>(w1, w2, wq, wkv, wo, dw, dwb, relb,
                                        w1p, w2p, wqp, wkp, wvp, wop,
                                        dwp, dwbp, bias);
    attn_kernel<<<8192, 128, 0, stream>>>(x, n1g, n1b, bq, bkv, bo,
                                          wqp, wkp, wvp, wop,
                                          (const float4*)bias, x1);
    leff_kernel_gw<<<8192, 256, 0, stream>>>(x1, n2g, n2b, b1, b2,
                                             w1p, w2p, dwp, dwbp, out);
}

// Round 16
// 131.159 us; speedup vs baseline: 1.2477x; 1.0699x over previous
//
#include <hip/hip_runtime.h>
#include <hip/hip_bf16.h>
#include <math.h>

// Problem constants (B=8, H=W=256, C=32, WIN=8, HEADS=2, DH=16, HIDDEN=128)
#define IMG   256
#define HWTOK 65536
#define CH    32

typedef __attribute__((ext_vector_type(8))) _Float16 half8v;    // 8 fp16
typedef __attribute__((ext_vector_type(2))) _Float16 half2v;    // 2 fp16
typedef __attribute__((ext_vector_type(4))) float floatx4;

__device__ __forceinline__ unsigned short f2h(float f) {
    _Float16 h = (_Float16)f;
    return __builtin_bit_cast(unsigned short, h);
}
__device__ __forceinline__ half2v pkrtz(float a, float b) {
    return __builtin_bit_cast(half2v, __builtin_amdgcn_cvt_pkrtz(a, b));
}
__device__ __forceinline__ unsigned packh2(float a, float b) {
    return __builtin_bit_cast(unsigned, __builtin_amdgcn_cvt_pkrtz(a, b));
}

// GELU via odd Taylor of Phi(v) = 0.5 + v*p(v^2), packed fp16.
__device__ __forceinline__ half2v gelu2v(half2v v) {
    const half2v hi = (half2v)(_Float16)( 2.0f);
    const half2v lo = (half2v)(_Float16)(-2.0f);
    const half2v vc = __builtin_elementwise_min(__builtin_elementwise_max(v, lo), hi);
    const half2v s  = vc * vc;
    half2v p = s * (half2v)(_Float16)(-1.18726e-3f) + (half2v)(_Float16)(9.97356e-3f);
    p = s * p + (half2v)(_Float16)(-6.64904e-2f);
    p = s * p + (half2v)(_Float16)( 3.989423e-1f);
    return v * (vc * p + (half2v)(_Float16)(0.5f));
}

// ---------------------------------------------------------------------------
// Prep: one-shot marshalling into workspace (29 blocks x 256). (unchanged)
// ---------------------------------------------------------------------------
__global__ __launch_bounds__(256) void prep_kernel(
    const float* __restrict__ w1, const float* __restrict__ w2,
    const float* __restrict__ wq, const float* __restrict__ wkv,
    const float* __restrict__ wo, const float* __restrict__ dw,
    const float* __restrict__ dwb, const float* __restrict__ relb,
    unsigned short* __restrict__ w1p, unsigned short* __restrict__ w2p,
    unsigned short* __restrict__ wqp, unsigned short* __restrict__ wkp,
    unsigned short* __restrict__ wvp, unsigned short* __restrict__ wop,
    unsigned short* __restrict__ dwp, unsigned short* __restrict__ dwbp,
    float* __restrict__ biasf)
{
    const float LOG2E = 1.4426950408889634f;
    const float QSC   = 0.25f * LOG2E;
    const int bid = blockIdx.x, tid = threadIdx.x;

    if (bid < 16) {                       // leff FC weights
        const int t = bid * 256 + tid;
        const int row = t >> 5, k = t & 31;
        const int bl = row >> 5, wi = row & 31;
        const int j = bl * 32 + ((wi & 15) << 1) + (wi >> 4);
        w1p[t] = f2h(w1[k * 128 + j]);
        const int n = t >> 7, kk = t & 127;
        w2p[t] = f2h(w2[kk * 32 + n]);
    } else if (bid < 20) {                // attn weights, frag layout
        const int u = (bid - 16) * 256 + tid;
        const int h = u >> 9, rem = u & 511;
        const int col = rem >> 5, k = rem & 31;
        wqp[u] = f2h(wq [k * 32 + h * 16 + col] * QSC);
        wkp[u] = f2h(wkv[k * 64 + h * 16 + col]);
        wvp[u] = f2h(wkv[k * 64 + 32 + h * 16 + col]);
        const int n = u >> 5, kk2 = u & 31;
        wop[u] = f2h(wo[kk2 * 32 + n]);
    } else if (bid < 28) {                // bias C-fragment table
        const int g = (bid - 20) * 256 + tid;
        const int h = g >> 10, nt = (g >> 8) & 3, mt = (g >> 6) & 3, l = g & 63;
        const int q = nt * 16 + (l & 15);
        const int mb = mt * 16 + (l >> 4) * 4;
        const int qy = q >> 3, qx = q & 7;
        #pragma unroll
        for (int r = 0; r < 4; ++r) {
            const int m = mb + r;
            const int my = m >> 3, mx = m & 7;
            const int idx = (qy - my + 7) * 15 + (qx - mx + 7);
            biasf[g * 4 + r] = relb[idx * 2 + h] * LOG2E;
        }
    } else {                              // dw pack
        for (int e = tid; e < 1280; e += 256) {
            if (e < 1152) dwp[e] = f2h(dw[(e & 127) * 9 + (e >> 7)]);
            else          dwbp[e - 1152] = f2h(dwb[e - 1152]);
        }
    }
}

// ---------------------------------------------------------------------------
// Kernel 1: LN1 + window attention + proj + residual.
// ONE window per 256-thread block (4 waves = (head h, half s)).
// Same LDS (34,816 B -> 3 blocks/CU) but 12 waves/CU (was 6): each wave does
// HALF the per-head mt/nt work.  P-rows and denoms stay wave-local, so the
// barrier structure is unchanged (4 barriers).
// ---------------------------------------------------------------------------
__global__ __launch_bounds__(256, 3) void attn_kernel(
    const float* __restrict__ x,
    const float* __restrict__ n1g, const float* __restrict__ n1b,
    const float* __restrict__ bq,  const float* __restrict__ bkv,
    const float* __restrict__ bo,
    const unsigned short* __restrict__ wqp,
    const unsigned short* __restrict__ wkp,
    const unsigned short* __restrict__ wvp,
    const unsigned short* __restrict__ wop,
    const float4* __restrict__ biasf4,
    float* __restrict__ x1)
{
    struct Win {
        union {
            unsigned short xn[64][40];    // 5120
            unsigned short P[2][64][72];  // 18432 (max member)
            unsigned short O[64][40];
        } u;
        unsigned short Q[64][40];         // 5120
        unsigned short K[64][48];         // 6144 (cols 16..31 zero mask)
        unsigned short VT[2][16][72];     // 4608
    };
    __shared__ Win S;                     // 34304
    __shared__ float denom[2][64];        // 512  -> 34816 B total

    const int tid = threadIdx.x;
    const int wv  = tid >> 6;             // wave 0..3
    const int h   = wv & 1;               // head
    const int s2  = wv >> 1;              // half: mt/nt in {2*s2, 2*s2+1}
    const int l   = tid & 63;
    const int lm  = l & 15, lq = l >> 4;

    const int win = blockIdx.x;
    const int b   = win >> 10;
    const int wh  = (win >> 5) & 31, ww = win & 31;
    const size_t wbase = ((size_t)b * HWTOK + (wh * 8) * IMG + ww * 8) * CH;

    const float LOG2E = 1.4426950408889634f;
    const float QSC   = 0.25f * LOG2E;

    // ---- weight B-frags: single b128 loads from prepped tables ----
    const half8v bwq  = *(const half8v*)&wqp[h * 512 + lm * 32 + lq * 8];
    const half8v bwk  = *(const half8v*)&wkp[h * 512 + lm * 32 + lq * 8];
    const half8v bwv  = *(const half8v*)&wvp[h * 512 + lm * 32 + lq * 8];
    const half8v bwo0 = *(const half8v*)&wop[lm * 32 + lq * 8];
    const half8v bwo1 = *(const half8v*)&wop[(16 + lm) * 32 + lq * 8];

    // ---- LN staging: 4 threads per token (8 ch each, 2-level shfl) ----
    {
        const int tok = tid >> 2, q4 = tid & 3;
        const size_t sbase = wbase
            + (size_t)((tok >> 3) * IMG + (tok & 7)) * CH + q4 * 8;
        const float4* xp = (const float4*)(x + sbase);
        float v[8];
        float s = 0.f;
        #pragma unroll
        for (int i = 0; i < 2; ++i) {
            const float4 t = xp[i];
            v[i*4+0]=t.x; v[i*4+1]=t.y; v[i*4+2]=t.z; v[i*4+3]=t.w;
            s += t.x + t.y + t.z + t.w;
        }
        s += __shfl_xor(s, 1);
        s += __shfl_xor(s, 2);
        const float mu = s * (1.f / 32.f);
        float qq = 0.f;
        #pragma unroll
        for (int c = 0; c < 8; ++c) { const float d = v[c] - mu; qq += d * d; }
        qq += __shfl_xor(qq, 1);
        qq += __shfl_xor(qq, 2);
        const float inv = rsqrtf(qq * (1.f / 32.f) + 1e-5f);
        unsigned pk[4];
        #pragma unroll
        for (int j = 0; j < 4; ++j) {
            const int c = q4 * 8 + 2 * j;
            pk[j] = packh2(v[2*j]   * inv - mu * inv * 1.f, 0.f);   // placeholder
        }
        // (recompute properly — affine LN with gamma/beta)
        #pragma unroll
        for (int j = 0; j < 4; ++j) {
            const int c = q4 * 8 + 2 * j;
            pk[j] = packh2((v[2*j]   - mu) * inv * n1g[c]   + n1b[c],
                           (v[2*j+1] - mu) * inv * n1g[c+1] + n1b[c+1]);
        }
        *(uint4*)&S.u.xn[tok][q4 * 8] = *(uint4*)&pk[0];
        if (q4 < 2) {                                // zero K mask cols 16..31
            const uint4 z = {0u, 0u, 0u, 0u};
            *(uint4*)&S.K[tok][16 + q4 * 8] = z;
        }
    }
    __syncthreads();                               // (1) xn ready

    const float bqv = bq[h*16 + lm] * QSC;
    const float bkv_ = bkv[h*16 + lm];
    const float bvv = bkv[32 + h*16 + lm];
    const floatx4 cq = {bqv, bqv, bqv, bqv};
    const floatx4 ck = {bkv_, bkv_, bkv_, bkv_};
    const floatx4 cv = {bvv, bvv, bvv, bvv};
    const floatx4 zero = {0.f, 0.f, 0.f, 0.f};

    // ---- QKV projection (own head, own mt half) ----
    #pragma unroll
    for (int mi = 0; mi < 2; ++mi) {
        const int mt = 2*s2 + mi;
        const half8v a = *(const half8v*)&S.u.xn[mt*16 + lm][lq*8];
        const floatx4 dq = __builtin_amdgcn_mfma_f32_16x16x32_f16(a, bwq, cq, 0,0,0);
        const floatx4 dk = __builtin_amdgcn_mfma_f32_16x16x32_f16(a, bwk, ck, 0,0,0);
        const floatx4 dv = __builtin_amdgcn_mfma_f32_16x16x32_f16(a, bwv, cv, 0,0,0);
        const int r0 = mt*16 + lq*4;
        #pragma unroll
        for (int r = 0; r < 4; ++r) {
            S.Q[r0 + r][h*16 + lm] = f2h(dq[r]);
            S.K[r0 + r][h*32 + lm] = f2h(dk[r]);   // head h dims at cols 32h
        }
        uint2 vv;
        vv.x = packh2(dv[0], dv[1]);
        vv.y = packh2(dv[2], dv[3]);
        *(uint2*)&S.VT[h][lm][r0] = vv;            // V^T[dim][token]
    }
    __syncthreads();                               // (2) Q/K/V complete

    // ---- S^T = mfma(K, Q), bias via C-init; own nt half ----
    half8v ak[4];
    #pragma unroll
    for (int mt = 0; mt < 4; ++mt)
        ak[mt] = *(const half8v*)&S.K[mt*16 + lm][h*16 + lq*8];

    #pragma unroll
    for (int ni = 0; ni < 2; ++ni) {
        const int nt = 2*s2 + ni;
        const half8v bq_ = *(const half8v*)&S.Q[nt*16 + lm][lq*8];
        float sum = 0.f;
        #pragma unroll
        for (int mt = 0; mt < 4; ++mt) {
            const float4 cb = biasf4[(h*16 + nt*4 + mt) * 64 + l];
            const floatx4 C = {cb.x, cb.y, cb.z, cb.w};
            const floatx4 d = __builtin_amdgcn_mfma_f32_16x16x32_f16(ak[mt], bq_, C, 0,0,0);
            const float e0 = exp2f(d[0]);
            const float e1 = exp2f(d[1]);
            const float e2 = exp2f(d[2]);
            const float e3 = exp2f(d[3]);
            sum += (e0 + e1) + (e2 + e3);
            uint2 pw;
            pw.x = packh2(e0, e1);
            pw.y = packh2(e2, e3);
            *(uint2*)&S.u.P[h][nt*16 + lm][mt*16 + lq*4] = pw;
        }
        sum += __shfl_xor(sum, 16);
        sum += __shfl_xor(sum, 32);
        if (l < 16) denom[h][nt*16 + l] = __frcp_rn(sum);
    }

    // ---- PV + normalize (own mt half; P rows + denom are wave-local) ----
    const half8v bva = *(const half8v*)&S.VT[h][lm][lq*8];
    const half8v bvb = *(const half8v*)&S.VT[h][lm][32 + lq*8];
    float oreg[8];
    #pragma unroll
    for (int mi = 0; mi < 2; ++mi) {
        const int mt = 2*s2 + mi;
        const half8v ap0 = *(const half8v*)&S.u.P[h][mt*16 + lm][lq*8];
        const half8v ap1 = *(const half8v*)&S.u.P[h][mt*16 + lm][32 + lq*8];
        floatx4 ov = __builtin_amdgcn_mfma_f32_16x16x32_f16(ap0, bva, zero, 0,0,0);
        ov         = __builtin_amdgcn_mfma_f32_16x16x32_f16(ap1, bvb, ov,   0,0,0);
        const float4 dn = *(const float4*)&denom[h][mt*16 + lq*4];
        oreg[mi*4+0] = ov[0] * dn.x;
        oreg[mi*4+1] = ov[1] * dn.y;
        oreg[mi*4+2] = ov[2] * dn.z;
        oreg[mi*4+3] = ov[3] * dn.w;
    }
    __syncthreads();                 // (3) PV reads done before O clobbers P

    #pragma unroll
    for (int mi = 0; mi < 2; ++mi) {
        const int mt = 2*s2 + mi;
        #pragma unroll
        for (int r = 0; r < 4; ++r)
            S.u.O[mt*16 + lq*4 + r][h*16 + lm] = f2h(oreg[mi*4 + r]);
    }
    __syncthreads();                 // (4) O complete

    // ---- out-projection + residual: wave wv handles mt = wv ----
    {
        const int mt = wv;
        const float bo0 = bo[lm], bo1 = bo[16 + lm];
        const floatx4 co0 = {bo0, bo0, bo0, bo0};
        const floatx4 co1 = {bo1, bo1, bo1, bo1};
        const half8v aO = *(const half8v*)&S.u.O[mt*16 + lm][lq*8];
        const floatx4 d0 = __builtin_amdgcn_mfma_f32_16x16x32_f16(aO, bwo0, co0, 0,0,0);
        const floatx4 d1 = __builtin_amdgcn_mfma_f32_16x16x32_f16(aO, bwo1, co1, 0,0,0);
        #pragma unroll
        for (int r = 0; r < 4; ++r) {
            const int t = mt*16 + lq*4 + r;
            const size_t g = wbase + (size_t)((t >> 3) * IMG + (t & 7)) * CH;
            x1[g + lm]      = x[g + lm]      + d0[r];
            x1[g + 16 + lm] = x[g + 16 + lm] + d1[r];
        }
    }
}

// ---------------------------------------------------------------------------
// Kernel 2: fused LeFF — 512 threads/block (8 waves), same LDS 34,560 B
// -> 3 blocks/CU = 24 waves/CU (2x round-15 wave parallelism).
//   P1: wave (cb = wv>>1, mhalf = wv&1): col block cb, mt half.
//   P2: 2 channels/thread (64 ch-pairs x 8 rows).
//   P3: wave (mt = wv>>1, nt = wv&1): one MFMA quadrant.
// ---------------------------------------------------------------------------
__global__ __launch_bounds__(512, 6) void leff_kernel_gw(
    const float* __restrict__ x1,
    const float* __restrict__ n2g, const float* __restrict__ n2b,
    const float* __restrict__ b1,  const float* __restrict__ b2,
    const unsigned short* __restrict__ w1p,
    const unsigned short* __restrict__ w2p,
    const unsigned short* __restrict__ dwp,
    const unsigned short* __restrict__ dwbp,
    float* __restrict__ out)
{
    __shared__ __align__(16) unsigned short xnA[112][40];   // 8960 B
    union HG {
        unsigned short hid[100][128];   // 25600 B
        unsigned short glA[64][132];    // 16896 B (inside hid region)
    };
    __shared__ __align__(16) HG hg;                         // total 34560 B

    const int blk = blockIdx.x;
    const int b = blk >> 10, tyb = (blk >> 5) & 31, txb = blk & 31;
    const int y0 = tyb * 8, x0 = txb * 8;
    const int tid = threadIdx.x;
    const int wv = tid >> 6;           // wave 0..7
    const int l  = tid & 63;
    const int lm = l & 15;
    const int lq = l >> 4;
    const bool edge = (tyb == 0) | (tyb == 31) | (txb == 0) | (txb == 31);

    // ---- FC1 weight B-frags: wave (cb, mhalf) ----
    const int cb = wv >> 1, mhalf = wv & 1;
    const half8v bf0 = *(const half8v*)&w1p[(cb * 32 + lm) * 32 + lq * 8];
    const half8v bf1 = *(const half8v*)&w1p[(cb * 32 + 16 + lm) * 32 + lq * 8];

    // ---- P0: LN2, 4 threads per halo pixel (8 ch each) ----
    if (tid < 400) {
        const int px = tid >> 2, q4 = tid & 3;
        const int hy = px / 10, hx = px % 10;
        const int iy = y0 + hy - 1, ix = x0 + hx - 1;
        const bool inb = (iy >= 0 && iy < IMG && ix >= 0 && ix < IMG);
        unsigned pk[4];
        if (inb) {
            const size_t base = ((size_t)b * HWTOK + iy * IMG + ix) * CH + q4 * 8;
            const float4* xp = (const float4*)(x1 + base);
            float v[8];
            float s = 0.f;
            #pragma unroll
            for (int i = 0; i < 2; ++i) {
                const float4 t = xp[i];
                v[i*4+0]=t.x; v[i*4+1]=t.y; v[i*4+2]=t.z; v[i*4+3]=t.w;
                s += t.x + t.y + t.z + t.w;
            }
            s += __shfl_xor(s, 1);
            s += __shfl_xor(s, 2);
            const float mu = s * (1.f / 32.f);
            float qq = 0.f;
            #pragma unroll
            for (int c = 0; c < 8; ++c) { const float d = v[c]-mu; qq += d*d; }
            qq += __shfl_xor(qq, 1);
            qq += __shfl_xor(qq, 2);
            const float inv = rsqrtf(qq * (1.f/32.f) + 1e-5f);
            #pragma unroll
            for (int j = 0; j < 4; ++j) {
                const int c = q4 * 8 + 2 * j;
                pk[j] = packh2((v[2*j]   - mu) * inv * n2g[c]   + n2b[c],
                               (v[2*j+1] - mu) * inv * n2g[c+1] + n2b[c+1]);
            }
        } else {
            #pragma unroll
            for (int j = 0; j < 4; ++j) pk[j] = 0u;
        }
        *(uint4*)&xnA[px][q4 * 8] = *(uint4*)&pk[0];
    } else if (tid < 448) {
        const int t2 = tid - 400;                  // zero M-pad rows 100..111
        const uint4 z = {0u,0u,0u,0u};
        *(uint4*)&xnA[100 + (t2 >> 2)][(t2 & 3) * 8] = z;
    }
    __syncthreads();

    // ---- P1: FC1 MFMA (bias in C) -> packed GELU -> hid; own mt half ----
    {
        const int c0 = cb * 32 + 2 * lm;
        const float bias0 = b1[c0], bias1 = b1[c0 + 1];
        const floatx4 cb0 = {bias0, bias0, bias0, bias0};
        const floatx4 cb1 = {bias1, bias1, bias1, bias1};
        const int mt0 = mhalf ? 4 : 0;
        const int mtN = mhalf ? 7 : 4;
        for (int mt = mt0; mt < mtN; ++mt) {
            const half8v af = *(const half8v*)&xnA[mt * 16 + lm][lq * 8];
            floatx4 a0 = __builtin_amdgcn_mfma_f32_16x16x32_f16(af, bf0, cb0, 0, 0, 0);
            floatx4 a1 = __builtin_amdgcn_mfma_f32_16x16x32_f16(af, bf1, cb1, 0, 0, 0);
            #pragma unroll
            for (int r = 0; r < 4; ++r) {
                const int p = mt * 16 + lq * 4 + r;
                if (mt < 6 || p < 100) {
                    half2v g = gelu2v(pkrtz(a0[r], a1[r]));
                    unsigned int bits = __builtin_bit_cast(unsigned int, g);
                    if (edge) {
                        const int hy = (p * 205) >> 11;
                        const int hx = p - hy * 10;
                        const int iy = y0 + hy - 1, ix = x0 + hx - 1;
                        const bool inb = (iy >= 0) & (iy < IMG) & (ix >= 0) & (ix < IMG);
                        if (!inb) bits = 0u;
                    }
                    *(unsigned int*)&hg.hid[p][c0] = bits;
                }
            }
        }
    }
    __syncthreads();

    // ---- P2: dwconv 3x3, 2 channels/thread, row-blocked -> glA ----
    {
        const int jq = tid & 63, pg = tid >> 6;    // j0 = 2*jq; row pg
        const int j0 = 2 * jq;
        half2v dwa[9];
        #pragma unroll
        for (int t = 0; t < 9; ++t)
            dwa[t] = __builtin_bit_cast(half2v, *(const unsigned*)&dwp[t * 128 + j0]);
        half2v acc[8];
        {
            const half2v dba = __builtin_bit_cast(half2v, *(const unsigned*)&dwbp[j0]);
            #pragma unroll
            for (int i = 0; i < 8; ++i) acc[i] = dba;
        }
        #pragma unroll
        for (int ky = 0; ky < 3; ++ky) {
            unsigned rr[10];
            #pragma unroll
            for (int cx = 0; cx < 10; ++cx)
                rr[cx] = *(const unsigned*)&hg.hid[(pg + ky) * 10 + cx][j0];
            #pragma unroll
            for (int i = 0; i < 8; ++i)
                #pragma unroll
                for (int kx = 0; kx < 3; ++kx)
                    acc[i] = __builtin_bit_cast(half2v, rr[i + kx]) * dwa[ky*3+kx] + acc[i];
        }
        __syncthreads();          // ALL hid reads complete; glA may alias hid
        #pragma unroll
        for (int i = 0; i < 8; ++i) {
            const half2v g = gelu2v(acc[i]);
            *(unsigned*)&hg.glA[pg * 8 + i][j0] = __builtin_bit_cast(unsigned, g);
        }
    }
    __syncthreads();

    // ---- P3: FC2 MFMA (K=128, bias in C) + residual; one quadrant/wave ----
    {
        const int mt = wv >> 1, nt = wv & 1;
        half8v w2f[4];
        #pragma unroll
        for (int kc = 0; kc < 4; ++kc)
            w2f[kc] = *(const half8v*)&w2p[(nt*16 + lm) * 128 + kc*32 + lq*8];
        const int c = nt * 16 + lm;
        const float bias = b2[c];
        floatx4 acc = {bias, bias, bias, bias};
        #pragma unroll
        for (int kc = 0; kc < 4; ++kc) {
            const half8v a = *(const half8v*)&hg.glA[mt * 16 + lm][kc * 32 + lq * 8];
            acc = __builtin_amdgcn_mfma_f32_16x16x32_f16(a, w2f[kc], acc, 0, 0, 0);
        }
        #pragma unroll
        for (int r = 0; r < 4; ++r) {
            const int p = mt * 16 + lq * 4 + r;
            const int iy = y0 + (p >> 3), ix = x0 + (p & 7);
            const size_t g = ((size_t)b * HWTOK + iy * IMG + ix) * CH + c;
            out[g] = x1[g] + acc[r];
        }
    }
}

// ---------------------------------------------------------------------------
extern "C" void kernel_launch(void* const* d_in, const int* in_sizes, int n_in,
                              void* d_out, int out_size, void* d_ws, size_t ws_size,
                              hipStream_t stream)
{
    const float* x    = (const float*)d_in[0];
    const float* n1g  = (const float*)d_in[1];
    const float* n1b  = (const float*)d_in[2];
    const float* wq   = (const float*)d_in[3];
    const float* bq   = (const float*)d_in[4];
    const float* wkv  = (const float*)d_in[5];
    const float* bkv  = (const float*)d_in[6];
    const float* wo   = (const float*)d_in[7];
    const float* bo   = (const float*)d_in[8];
    const float* relb = (const float*)d_in[9];
    const float* n2g  = (const float*)d_in[10];
    const float* n2b  = (const float*)d_in[11];
    const float* w1   = (const float*)d_in[12];
    const float* b1   = (const float*)d_in[13];
    const float* dw   = (const float*)d_in[14];
    const float* dwb  = (const float*)d_in[15];
    const float* w2   = (const float*)d_in[16];
    const float* b2   = (const float*)d_in[17];

    float* out = (float*)d_out;
    float* x1  = (float*)d_ws;                       // 64 MB
    char* base = (char*)d_ws + (size_t)8 * HWTOK * CH * 4;
    unsigned short* w1p  = (unsigned short*)(base);           // 8192 B
    unsigned short* w2p  = (unsigned short*)(base + 8192);    // 8192 B
    unsigned short* wqp  = (unsigned short*)(base + 16384);   // 2048 B
    unsigned short* wkp  = (unsigned short*)(base + 18432);   // 2048 B
    unsigned short* wvp  = (unsigned short*)(base + 20480);   // 2048 B
    unsigned short* wop  = (unsigned short*)(base + 22528);   // 2048 B
    unsigned short* dwp  = (unsigned short*)(base + 24576);   // 2304 B
    unsigned short* dwbp = (unsigned short*)(base + 26880);   // 256 B
    float*          bias = (float*)(base + 28672);            // 32768 B

    prep_kernel<<<29, 256, 0, stream>>>(w1, w2, wq, wkv, wo, dw, dwb, relb,
                                        w1p, w2p, wqp, wkp, wvp, wop,
                                        dwp, dwbp, bias);
    attn_kernel<<<8192, 256, 0, stream>>>(x, n1g, n1b, bq, bkv, bo,
                                          wqp, wkp, wvp, wop,
                                          (const float4*)bias, x1);
    leff_kernel_gw<<<8192, 512, 0, stream>>>(x1, n2g, n2b, b1, b2,
                                             w1p, w2p, dwp, dwbp, out);
}